// Round 2
// baseline (5373.119 us; speedup 1.0000x reference)
//
#include <hip/hip_runtime.h>
#include <hip/hip_cooperative_groups.h>
#include <math.h>

namespace cg = cooperative_groups;

#define VOCAB 10000
#define VPAD  10048
#define EMBED 256
#define ENC   2048
#define DEC   512
#define ATT   512
#define B_    64
#define P_    49
#define T_    30
#define G4    2048   // 4*DEC
#define KC1   2560   // ENC + DEC
#define KC2   1024   // DEC + DEC

typedef __bf16 bf16_t;
typedef bf16_t bf16x8 __attribute__((ext_vector_type(8)));
typedef bf16_t bf16x4 __attribute__((ext_vector_type(4)));
typedef float  f32x4  __attribute__((ext_vector_type(4)));

__device__ __forceinline__ float sigf(float x) { return 1.f / (1.f + expf(-x)); }

// ---------------------------------------------------------------------------
// One-time prep: bias sums, bf16 conversions / repacks, embedding gather.
// ---------------------------------------------------------------------------
__global__ void prep_k(
    const float* __restrict__ b_ih1, const float* __restrict__ b_hh1, float* __restrict__ bsum1,
    const float* __restrict__ b_ih2, const float* __restrict__ b_hh2, float* __restrict__ bsum2,
    const float* __restrict__ W2,    bf16_t* __restrict__ W2b,
    const float* __restrict__ W1,    bf16_t* __restrict__ W1b,
    const float* __restrict__ W_ih1, bf16_t* __restrict__ Wihel, bf16_t* __restrict__ Wcat1b,
    const float* __restrict__ W_ih2, const float* __restrict__ W_hh1,
    const float* __restrict__ W_hh2, bf16_t* __restrict__ Wcat2b,
    const float* __restrict__ fc_W,  bf16_t* __restrict__ fcWb,
    const float* __restrict__ features, bf16_t* __restrict__ featb,
    const int* __restrict__ caps, const float* __restrict__ emb, bf16_t* __restrict__ xgb)
{
    long stride = (long)gridDim.x * blockDim.x;
    long i0 = (long)blockIdx.x * blockDim.x + threadIdx.x;
    for (long i = i0; i < 2048; i += stride) {
        bsum1[i] = b_ih1[i] + b_hh1[i];
        bsum2[i] = b_ih2[i] + b_hh2[i];
    }
    for (long i = i0; i < 512L * 512; i += stride) W2b[i] = (bf16_t)W2[i];
    for (long i = i0; i < 512L * 2048; i += stride) W1b[i] = (bf16_t)W1[i];
    for (long i = i0; i < 2048L * 256; i += stride) {
        long j = i >> 8, c = i & 255;
        Wihel[i] = (bf16_t)W_ih1[j * 2304 + c];
    }
    for (long i = i0; i < 2048L * 2560; i += stride) {
        long j = i / 2560, c = i - j * 2560;
        Wcat1b[i] = (bf16_t)(c < 2048 ? W_ih1[j * 2304 + 256 + c] : W_hh1[j * 512 + (c - 2048)]);
    }
    for (long i = i0; i < 2048L * 1024; i += stride) {
        long j = i >> 10, c = i & 1023;
        Wcat2b[i] = (bf16_t)(c < 512 ? W_ih2[j * 512 + c] : W_hh2[j * 512 + (c - 512)]);
    }
    for (long i = i0; i < (long)VPAD * 512; i += stride) {
        long r = i >> 9;
        fcWb[i] = (bf16_t)(r < VOCAB ? fc_W[i] : 0.f);
    }
    for (long i = i0; i < 3136L * 2048; i += stride) featb[i] = (bf16_t)features[i];
    for (long i = i0; i < 1920L * 256; i += stride) {
        long row = i >> 8, e = i & 255;
        long t = row >> 6, b = row & 63;
        int cap = caps[b * T_ + t];
        xgb[i] = (bf16_t)emb[(long)cap * 256 + e];
    }
}

// ---------------------------------------------------------------------------
// bf16 MFMA GEMM: C[M,N] = A[M,K] @ W[N,K]^T + bias[N].  M%64==0, K%64==0.
// tile 64x64, 4 waves (one 16-row M-tile each, 4 N-frags), K-chunk 64.
// MODE 0: bf16 out.  MODE 1: f32 out.  MODE 2: f32 out, fc row-remap + N guard.
// ---------------------------------------------------------------------------
template <int MODE>
__global__ __launch_bounds__(256) void mm_bf16(
    const bf16_t* __restrict__ A, int lda,
    const bf16_t* __restrict__ Bw, int ldb,
    const float* __restrict__ bias,
    float* __restrict__ outF, bf16_t* __restrict__ outB, int ldo,
    int N, int K)
{
    __shared__ bf16_t Apad[64][72];
    __shared__ bf16_t Bpad[64][72];
    const int bn = blockIdx.x * 64, bm = blockIdx.y * 64;
    const int tid = threadIdx.x;
    const int w = tid >> 6, l = tid & 63;
    f32x4 acc[4] = {};

    for (int k0 = 0; k0 < K; k0 += 64) {
        for (int c = tid; c < 512; c += 256) {
            int row = c >> 3, q = c & 7;
            *(bf16x8*)&Apad[row][q * 8] = *(const bf16x8*)&A[(size_t)(bm + row) * lda + k0 + q * 8];
            *(bf16x8*)&Bpad[row][q * 8] = *(const bf16x8*)&Bw[(size_t)(bn + row) * ldb + k0 + q * 8];
        }
        __syncthreads();
#pragma unroll
        for (int ks = 0; ks < 2; ++ks) {
            bf16x8 a8 = *(const bf16x8*)&Apad[w * 16 + (l & 15)][ks * 32 + (l >> 4) * 8];
#pragma unroll
            for (int nf = 0; nf < 4; ++nf) {
                bf16x8 b8 = *(const bf16x8*)&Bpad[nf * 16 + (l & 15)][ks * 32 + (l >> 4) * 8];
                acc[nf] = __builtin_amdgcn_mfma_f32_16x16x32_bf16(a8, b8, acc[nf], 0, 0, 0);
            }
        }
        __syncthreads();
    }

    int rbase = bm + w * 16 + (l >> 4) * 4;
    int cl = l & 15;
#pragma unroll
    for (int nf = 0; nf < 4; ++nf) {
        int col = bn + nf * 16 + cl;
#pragma unroll
        for (int j = 0; j < 4; ++j) {
            int row = rbase + j;
            float v = acc[nf][j];
            if (MODE == 0) {
                outB[(size_t)row * ldo + col] = (bf16_t)(v + bias[col]);
            } else if (MODE == 1) {
                outF[(size_t)row * ldo + col] = v + bias[col];
            } else {
                if (col < N) {
                    int orow = (row & 63) * T_ + (row >> 6);  // row = t*64+b -> out row b*T+t
                    outF[(size_t)orow * ldo + col] = v + bias[col];
                }
            }
        }
    }
}

// ---------------------------------------------------------------------------
// Persistent cooperative kernel: the whole 30-step recurrence.
// grid 256 blocks x 512 threads. Per step:
//   A: blocks 0..63 (b=bid): pw2(prev gates2) -> h2; hw = h2@W2^T+b2; score/
//      softmax; ctx -> XA1[:,0:2048] (bf16)
//   B: 256 blocks (nt=bid>>2: 32 cols, kh=bid&3: K 640): gates1 MFMA partials
//   C: blocks 0..63: pw1 (base xembb + 4 partials) -> c1, h1 -> XA1/XA2
//   D: 256 blocks (nt x kh: K 256): gates2 MFMA partials
// ---------------------------------------------------------------------------
struct PP {
    const bf16_t *featb, *fW1b, *W2b, *Wcat1b, *Wcat2b;
    const float *V, *bV, *b2, *bsum2, *xembb;
    bf16_t *XA1, *XA2, *h2allb;
    float *c1, *c2, *g1p, *g2p;
};

__global__ __launch_bounds__(512, 1) void persistent_k(PP p)
{
    cg::grid_group grid = cg::this_grid();
    const int bid = blockIdx.x;
    const int tid = threadIdx.x;
    const int w = tid >> 6, l = tid & 63;

    __shared__ union {
        struct { bf16_t A[64 * 136]; bf16_t Bm[32 * 136]; } g;
        struct { float h2s[DEC]; float hw[ATT]; float Vs[ATT]; float sc[64]; float wn[64]; } a;
    } sm;

    for (int t = 0; t <= T_; ++t) {
        // ---------------- PHASE A ----------------
        if (bid < B_) {
            const int b = bid;
            {
                int d = tid;  // 512 threads cover DEC
                if (t > 0) {
                    float gi = p.bsum2[d], gf = p.bsum2[DEC + d];
                    float gg = p.bsum2[2 * DEC + d], go = p.bsum2[3 * DEC + d];
                    const float* q = p.g2p + b * G4;
                    for (int kh = 0; kh < 4; ++kh) {
                        const float* qq = q + kh * (B_ * G4);
                        gi += qq[d]; gf += qq[DEC + d]; gg += qq[2 * DEC + d]; go += qq[3 * DEC + d];
                    }
                    float cp = p.c2[b * DEC + d];
                    float cn = sigf(gf) * cp + sigf(gi) * tanhf(gg);
                    p.c2[b * DEC + d] = cn;
                    float h = sigf(go) * tanhf(cn);
                    sm.a.h2s[d] = h;
                    p.XA2[b * KC2 + DEC + d] = (bf16_t)h;
                    p.h2allb[((size_t)(t - 1) * B_ + b) * DEC + d] = (bf16_t)h;
                } else {
                    sm.a.h2s[d] = 0.f;
                }
                sm.a.Vs[d] = p.V[d];
            }
            __syncthreads();
            if (t < T_) {
                // hw[a] = b2[a] + sum_d h2s[d]*W2[a][d]
                {
                    int a = tid;
                    float s = p.b2[a];
                    const bf16_t* wr = p.W2b + (size_t)a * DEC;
                    for (int d0 = 0; d0 < DEC; d0 += 8) {
                        bf16x8 w8 = *(const bf16x8*)&wr[d0];
#pragma unroll
                        for (int i = 0; i < 8; ++i) s += sm.a.h2s[d0 + i] * (float)w8[i];
                    }
                    sm.a.hw[a] = s;
                }
                __syncthreads();
                // score[p] = bV + sum_a tanh(fW1[b,p,a]+hw[a]) * V[a]
                {
                    float hwr[8], Vr[8];
#pragma unroll
                    for (int i = 0; i < 8; ++i) { hwr[i] = sm.a.hw[l * 8 + i]; Vr[i] = sm.a.Vs[l * 8 + i]; }
                    for (int pq = w; pq < P_; pq += 8) {
                        bf16x8 f8 = *(const bf16x8*)&p.fW1b[(size_t)(b * P_ + pq) * ATT + l * 8];
                        float s = 0.f;
#pragma unroll
                        for (int i = 0; i < 8; ++i) s += tanhf((float)f8[i] + hwr[i]) * Vr[i];
#pragma unroll
                        for (int o = 32; o; o >>= 1) s += __shfl_xor(s, o);
                        if (l == 0) sm.a.sc[pq] = s + p.bV[0];
                    }
                }
                __syncthreads();
                {
                    float m = -1e30f;
                    for (int q = 0; q < P_; ++q) m = fmaxf(m, sm.a.sc[q]);
                    float ss = 0.f;
                    for (int q = 0; q < P_; ++q) ss += expf(sm.a.sc[q] - m);
                    if (tid < P_) sm.a.wn[tid] = expf(sm.a.sc[tid] - m) / ss;
                }
                __syncthreads();
                // ctx: thread -> 4 contiguous e
                {
                    int e0 = tid * 4;
                    float a0 = 0, a1 = 0, a2 = 0, a3 = 0;
                    const bf16_t* fb = p.featb + (size_t)b * P_ * ENC + e0;
                    for (int q = 0; q < P_; ++q) {
                        bf16x4 f4 = *(const bf16x4*)&fb[(size_t)q * ENC];
                        float wq = sm.a.wn[q];
                        a0 += wq * (float)f4[0]; a1 += wq * (float)f4[1];
                        a2 += wq * (float)f4[2]; a3 += wq * (float)f4[3];
                    }
                    bf16x4 o4 = { (bf16_t)a0, (bf16_t)a1, (bf16_t)a2, (bf16_t)a3 };
                    *(bf16x4*)&p.XA1[(size_t)b * KC1 + e0] = o4;
                }
            }
        }
        grid.sync();
        if (t == T_) break;

        // ---------------- PHASE B: gates1 ----------------
        {
            const int nt = bid >> 2, kh = bid & 3;
            const int mt = w & 3, nh = w >> 2;
            f32x4 acc = {};
            const int kbase = kh * 640;
            for (int kc = 0; kc < 5; ++kc) {
                int k0 = kbase + kc * 128;
                for (int c = tid; c < 1536; c += 512) {
                    if (c < 1024) {
                        int row = c >> 4, q = c & 15;
                        *(bf16x8*)&sm.g.A[row * 136 + q * 8] =
                            *(const bf16x8*)&p.XA1[(size_t)row * KC1 + k0 + q * 8];
                    } else {
                        int c2 = c - 1024, row = c2 >> 4, q = c2 & 15;
                        *(bf16x8*)&sm.g.Bm[row * 136 + q * 8] =
                            *(const bf16x8*)&p.Wcat1b[(size_t)(nt * 32 + row) * KC1 + k0 + q * 8];
                    }
                }
                __syncthreads();
#pragma unroll
                for (int kk = 0; kk < 4; ++kk) {
                    bf16x8 a8 = *(const bf16x8*)&sm.g.A[(mt * 16 + (l & 15)) * 136 + kk * 32 + (l >> 4) * 8];
                    bf16x8 b8 = *(const bf16x8*)&sm.g.Bm[(nh * 16 + (l & 15)) * 136 + kk * 32 + (l >> 4) * 8];
                    acc = __builtin_amdgcn_mfma_f32_16x16x32_bf16(a8, b8, acc, 0, 0, 0);
                }
                __syncthreads();
            }
            float* gp = p.g1p + kh * (B_ * G4);
            int col = nt * 32 + nh * 16 + (l & 15);
            int r0 = mt * 16 + (l >> 4) * 4;
#pragma unroll
            for (int j = 0; j < 4; ++j) gp[(size_t)(r0 + j) * G4 + col] = acc[j];
        }
        grid.sync();

        // ---------------- PHASE C: pw1 ----------------
        if (bid < B_) {
            int idx = bid * 512 + tid;  // 0..32767
            int b = idx >> 9, d = idx & 511;
            const float* xb = p.xembb + (size_t)(t * B_ + b) * G4;
            float gi = xb[d], gf = xb[DEC + d], gg = xb[2 * DEC + d], go = xb[3 * DEC + d];
            for (int kh = 0; kh < 4; ++kh) {
                const float* qq = p.g1p + kh * (B_ * G4) + b * G4;
                gi += qq[d]; gf += qq[DEC + d]; gg += qq[2 * DEC + d]; go += qq[3 * DEC + d];
            }
            float cp = p.c1[idx];
            float cn = sigf(gf) * cp + sigf(gi) * tanhf(gg);
            p.c1[idx] = cn;
            float h = sigf(go) * tanhf(cn);
            bf16_t hb = (bf16_t)h;
            p.XA1[(size_t)b * KC1 + ENC + d] = hb;
            p.XA2[(size_t)b * KC2 + d] = hb;
        }
        grid.sync();

        // ---------------- PHASE D: gates2 ----------------
        {
            const int nt = bid >> 2, kh = bid & 3;
            const int mt = w & 3, nh = w >> 2;
            f32x4 acc = {};
            const int kbase = kh * 256;
            for (int kc = 0; kc < 2; ++kc) {
                int k0 = kbase + kc * 128;
                for (int c = tid; c < 1536; c += 512) {
                    if (c < 1024) {
                        int row = c >> 4, q = c & 15;
                        *(bf16x8*)&sm.g.A[row * 136 + q * 8] =
                            *(const bf16x8*)&p.XA2[(size_t)row * KC2 + k0 + q * 8];
                    } else {
                        int c2 = c - 1024, row = c2 >> 4, q = c2 & 15;
                        *(bf16x8*)&sm.g.Bm[row * 136 + q * 8] =
                            *(const bf16x8*)&p.Wcat2b[(size_t)(nt * 32 + row) * KC2 + k0 + q * 8];
                    }
                }
                __syncthreads();
#pragma unroll
                for (int kk = 0; kk < 4; ++kk) {
                    bf16x8 a8 = *(const bf16x8*)&sm.g.A[(mt * 16 + (l & 15)) * 136 + kk * 32 + (l >> 4) * 8];
                    bf16x8 b8 = *(const bf16x8*)&sm.g.Bm[(nh * 16 + (l & 15)) * 136 + kk * 32 + (l >> 4) * 8];
                    acc = __builtin_amdgcn_mfma_f32_16x16x32_bf16(a8, b8, acc, 0, 0, 0);
                }
                __syncthreads();
            }
            float* gp = p.g2p + kh * (B_ * G4);
            int col = nt * 32 + nh * 16 + (l & 15);
            int r0 = mt * 16 + (l >> 4) * 4;
#pragma unroll
            for (int j = 0; j < 4; ++j) gp[(size_t)(r0 + j) * G4 + col] = acc[j];
        }
        grid.sync();
    }
}

// ---------------------------------------------------------------------------
extern "C" void kernel_launch(void* const* d_in, const int* in_sizes, int n_in,
                              void* d_out, int out_size, void* d_ws, size_t ws_size,
                              hipStream_t stream)
{
    const float* features = (const float*)d_in[0];
    const int*   captions = (const int*)d_in[1];
    const float* emb   = (const float*)d_in[2];
    const float* W1    = (const float*)d_in[3];
    const float* b1    = (const float*)d_in[4];
    const float* W2    = (const float*)d_in[5];
    const float* b2    = (const float*)d_in[6];
    const float* V     = (const float*)d_in[7];
    const float* bV    = (const float*)d_in[8];
    const float* W_ih1 = (const float*)d_in[9];
    const float* W_hh1 = (const float*)d_in[10];
    const float* b_ih1 = (const float*)d_in[11];
    const float* b_hh1 = (const float*)d_in[12];
    const float* W_ih2 = (const float*)d_in[13];
    const float* W_hh2 = (const float*)d_in[14];
    const float* b_ih2 = (const float*)d_in[15];
    const float* b_hh2 = (const float*)d_in[16];
    const float* fc_W  = (const float*)d_in[17];
    const float* fc_b  = (const float*)d_in[18];
    float* out = (float*)d_out;

    char* ws = (char*)d_ws;
    size_t off = 0;
    auto alloc = [&](size_t nbytes) {
        char* pp = ws + off;
        off = (off + nbytes + 255) & ~(size_t)255;
        return pp;
    };
    bf16_t* featb  = (bf16_t*)alloc(3136L * 2048 * 2);
    bf16_t* fW1b   = (bf16_t*)alloc(3136L * 512 * 2);
    bf16_t* W1b    = (bf16_t*)alloc(512L * 2048 * 2);
    bf16_t* W2b    = (bf16_t*)alloc(512L * 512 * 2);
    bf16_t* Wihel  = (bf16_t*)alloc(2048L * 256 * 2);
    bf16_t* Wcat1b = (bf16_t*)alloc(2048L * 2560 * 2);
    bf16_t* Wcat2b = (bf16_t*)alloc(2048L * 1024 * 2);
    bf16_t* fcWb   = (bf16_t*)alloc((size_t)VPAD * 512 * 2);
    bf16_t* xgb    = (bf16_t*)alloc(1920L * 256 * 2);
    float*  xembb  = (float*)alloc(1920L * 2048 * 4);
    float*  bsum1  = (float*)alloc(2048 * 4);
    float*  bsum2  = (float*)alloc(2048 * 4);
    bf16_t* XA1    = (bf16_t*)alloc((size_t)B_ * KC1 * 2);
    bf16_t* XA2    = (bf16_t*)alloc((size_t)B_ * KC2 * 2);
    float*  g1p    = (float*)alloc(4L * B_ * G4 * 4);
    float*  g2p    = (float*)alloc(4L * B_ * G4 * 4);
    float*  c1     = (float*)alloc((size_t)B_ * DEC * 4);
    float*  c2     = (float*)alloc((size_t)B_ * DEC * 4);
    bf16_t* h2allb = (bf16_t*)alloc(1920L * 512 * 2);

    hipMemsetAsync(XA1, 0, (size_t)B_ * KC1 * 2, stream);
    hipMemsetAsync(XA2, 0, (size_t)B_ * KC2 * 2, stream);
    hipMemsetAsync(c1, 0, (size_t)B_ * DEC * 4, stream);
    hipMemsetAsync(c2, 0, (size_t)B_ * DEC * 4, stream);

    prep_k<<<4096, 256, 0, stream>>>(
        b_ih1, b_hh1, bsum1, b_ih2, b_hh2, bsum2,
        W2, W2b, W1, W1b, W_ih1, Wihel, Wcat1b,
        W_ih2, W_hh1, W_hh2, Wcat2b, fc_W, fcWb,
        features, featb, captions, emb, xgb);

    // fW1b = features @ W1^T + b1  (bf16 out)
    mm_bf16<0><<<dim3(ATT / 64, (B_ * P_) / 64), 256, 0, stream>>>(
        featb, ENC, W1b, ENC, b1, nullptr, fW1b, ATT, ATT, ENC);
    // xembb = xg @ Wih1[:, :256]^T + (b_ih1+b_hh1)  (f32 out)
    mm_bf16<1><<<dim3(G4 / 64, (T_ * B_) / 64), 256, 0, stream>>>(
        xgb, EMBED, Wihel, EMBED, bsum1, xembb, nullptr, G4, G4, EMBED);

    PP pp { featb, fW1b, W2b, Wcat1b, Wcat2b,
            V, bV, b2, bsum2, xembb,
            XA1, XA2, h2allb, c1, c2, g1p, g2p };
    void* args[] = { &pp };
    hipLaunchCooperativeKernel((const void*)persistent_k, dim3(256), dim3(512), args, 0, stream);

    // out = h2all @ fc_W^T + fc_b  (f32 out, row remap t*64+b -> b*T+t)
    mm_bf16<2><<<dim3(VPAD / 64, (T_ * B_) / 64), 256, 0, stream>>>(
        h2allb, DEC, fcWb, DEC, fc_b, out, nullptr, VOCAB, VOCAB, DEC);
}

// Round 6
// 2699.619 us; speedup vs baseline: 1.9903x; 1.9903x over previous
//
#include <hip/hip_runtime.h>
#include <math.h>

#define VOCAB 10000
#define VPAD  10048
#define EMBED 256
#define ENC   2048
#define DEC   512
#define ATT   512
#define B_    64
#define P_    49
#define T_    30
#define G4    2048   // 4*DEC
#define KC1   2560   // ENC + DEC
#define KC2   1024   // DEC + DEC

typedef __bf16 bf16_t;
typedef bf16_t bf16x8 __attribute__((ext_vector_type(8)));
typedef float  f32x4  __attribute__((ext_vector_type(4)));

__device__ __forceinline__ float sigf(float x) { return 1.f / (1.f + expf(-x)); }

// ---------------------------------------------------------------------------
// Per-call state init: zero slice 0 of h1s/h2s/h2f32 and both c slices.
// (Own kernel, not hipMemsetAsync — fewer graph-node types in play.)
// 256 blocks x 256 threads = 65536 threads exactly.
// ---------------------------------------------------------------------------
__global__ void zero_k(bf16_t* __restrict__ h1s0, bf16_t* __restrict__ h2s0,
                       float* __restrict__ h2f0, float* __restrict__ c1s,
                       float* __restrict__ c2s)
{
    int i = blockIdx.x * 256 + threadIdx.x;
    if (i < 32768) { h1s0[i] = (bf16_t)0.f; h2s0[i] = (bf16_t)0.f; h2f0[i] = 0.f; }
    c1s[i] = 0.f;
    c2s[i] = 0.f;
}

// ---------------------------------------------------------------------------
// One-time prep. Weight fragment packing for the step kernels:
// fp1[((nb*80 + kf)*4 + s)*512 + l*8 + j] = Wcat1[c][k],
//   c = s*512 + nb*16 + (l&15), k = kf*32 + (l>>4)*8 + j   (nb<32, kf<80)
// fp2 same with kf<32, Wcat2.  (Verified in round 5 — validation passed.)
// ---------------------------------------------------------------------------
__global__ void prep_k(
    const float* __restrict__ b_ih1, const float* __restrict__ b_hh1, float* __restrict__ bsum1,
    const float* __restrict__ b_ih2, const float* __restrict__ b_hh2, float* __restrict__ bsum2,
    const float* __restrict__ W2,    bf16_t* __restrict__ W2tb,
    const float* __restrict__ W1,    bf16_t* __restrict__ W1b,
    const float* __restrict__ W_ih1, bf16_t* __restrict__ Wihel, bf16_t* __restrict__ fp1,
    const float* __restrict__ W_ih2, const float* __restrict__ W_hh1,
    const float* __restrict__ W_hh2, bf16_t* __restrict__ fp2,
    const float* __restrict__ fc_W,  bf16_t* __restrict__ fcWb,
    const float* __restrict__ features, bf16_t* __restrict__ featb,
    const int* __restrict__ caps, const float* __restrict__ emb, bf16_t* __restrict__ xgb)
{
    long stride = (long)gridDim.x * blockDim.x;
    long i0 = (long)blockIdx.x * blockDim.x + threadIdx.x;
    for (long i = i0; i < 2048; i += stride) {
        bsum1[i] = b_ih1[i] + b_hh1[i];
        bsum2[i] = b_ih2[i] + b_hh2[i];
    }
    for (long i = i0; i < 512L * 512; i += stride) {     // W2tb[d][a] = W2[a][d]
        long d = i >> 9, a = i & 511;
        W2tb[i] = (bf16_t)W2[a * 512 + d];
    }
    for (long i = i0; i < 512L * 2048; i += stride) W1b[i] = (bf16_t)W1[i];
    for (long i = i0; i < 2048L * 256; i += stride) {
        long j = i >> 8, c = i & 255;
        Wihel[i] = (bf16_t)W_ih1[j * 2304 + c];
    }
    for (long i = i0; i < 2048L * 2560; i += stride) {   // fp1
        long j8 = i & 7, lq = (i >> 3) & 63, s = (i >> 9) & 3, nk = i >> 11;
        long kf = nk % 80, nb = nk / 80;
        long c = s * 512 + nb * 16 + (lq & 15);
        long k = kf * 32 + (lq >> 4) * 8 + j8;
        fp1[i] = (bf16_t)(k < 2048 ? W_ih1[c * 2304 + 256 + k] : W_hh1[c * 512 + (k - 2048)]);
    }
    for (long i = i0; i < 2048L * 1024; i += stride) {   // fp2
        long j8 = i & 7, lq = (i >> 3) & 63, s = (i >> 9) & 3, nk = i >> 11;
        long kf = nk & 31, nb = nk >> 5;
        long c = s * 512 + nb * 16 + (lq & 15);
        long k = kf * 32 + (lq >> 4) * 8 + j8;
        fp2[i] = (bf16_t)(k < 512 ? W_ih2[c * 512 + k] : W_hh2[c * 512 + (k - 512)]);
    }
    for (long i = i0; i < (long)VPAD * 512; i += stride) {
        long r = i >> 9;
        fcWb[i] = (bf16_t)(r < VOCAB ? fc_W[i] : 0.f);
    }
    for (long i = i0; i < 3136L * 2048; i += stride) featb[i] = (bf16_t)features[i];
    for (long i = i0; i < 1920L * 256; i += stride) {
        long row = i >> 8, e = i & 255;
        long tq = row >> 6, b = row & 63;
        int cap = caps[b * T_ + tq];
        xgb[i] = (bf16_t)emb[(long)cap * 256 + e];
    }
}

// ---------------------------------------------------------------------------
// bf16 MFMA GEMM (bulk GEMMs): C[M,N] = A[M,K] @ W[N,K]^T + bias[N].
// MODE 0: bf16 out. MODE 2: f32 out, fc row-remap + N guard.
// (Verified end-to-end in rounds 2 and 5.)
// ---------------------------------------------------------------------------
template <int MODE>
__global__ __launch_bounds__(256) void mm_bf16(
    const bf16_t* __restrict__ A, int lda,
    const bf16_t* __restrict__ Bw, int ldb,
    const float* __restrict__ bias,
    float* __restrict__ outF, bf16_t* __restrict__ outB, int ldo,
    int N, int K)
{
    __shared__ bf16_t Apad[64][72];
    __shared__ bf16_t Bpad[64][72];
    const int bn = blockIdx.x * 64, bm = blockIdx.y * 64;
    const int tid = threadIdx.x;
    const int w = tid >> 6, l = tid & 63;
    f32x4 acc[4] = {};

    for (int k0 = 0; k0 < K; k0 += 64) {
        for (int c = tid; c < 512; c += 256) {
            int row = c >> 3, q = c & 7;
            *(bf16x8*)&Apad[row][q * 8] = *(const bf16x8*)&A[(size_t)(bm + row) * lda + k0 + q * 8];
            *(bf16x8*)&Bpad[row][q * 8] = *(const bf16x8*)&Bw[(size_t)(bn + row) * ldb + k0 + q * 8];
        }
        __syncthreads();
#pragma unroll
        for (int ks = 0; ks < 2; ++ks) {
            bf16x8 a8 = *(const bf16x8*)&Apad[w * 16 + (l & 15)][ks * 32 + (l >> 4) * 8];
#pragma unroll
            for (int nf = 0; nf < 4; ++nf) {
                bf16x8 b8 = *(const bf16x8*)&Bpad[nf * 16 + (l & 15)][ks * 32 + (l >> 4) * 8];
                acc[nf] = __builtin_amdgcn_mfma_f32_16x16x32_bf16(a8, b8, acc[nf], 0, 0, 0);
            }
        }
        __syncthreads();
    }

    int rbase = bm + w * 16 + (l >> 4) * 4;
    int cl = l & 15;
#pragma unroll
    for (int nf = 0; nf < 4; ++nf) {
        int col = bn + nf * 16 + cl;
#pragma unroll
        for (int j = 0; j < 4; ++j) {
            int row = rbase + j;
            float v = acc[nf][j];
            if (MODE == 0) {
                outB[(size_t)row * ldo + col] = (bf16_t)(v + bias[col]);
            } else {
                if (col < N) {
                    int orow = (row & 63) * T_ + (row >> 6);  // t*64+b -> b*T+t
                    outF[(size_t)orow * ldo + col] = v + bias[col];
                }
            }
        }
    }
}

// ---------------------------------------------------------------------------
// Per-step kernel 1: attention. 64 blocks (one per batch), 256 threads.
// Reads h2f32 slice t (write-once, produced by g2 of step t-1 / zero_k).
// Writes ctx -> ctxb (standalone [64][2048], rewritten every step before read).
// ---------------------------------------------------------------------------
__global__ __launch_bounds__(256) void attn_k(
    const float* __restrict__ h2r, const bf16_t* __restrict__ W2tb,
    const float* __restrict__ b2, const bf16_t* __restrict__ fW1b,
    const float* __restrict__ V, const float* __restrict__ bV,
    const bf16_t* __restrict__ featb, bf16_t* __restrict__ ctxb)
{
    const int b = blockIdx.x, tid = threadIdx.x;
    const int w = tid >> 6, l = tid & 63;
    __shared__ float h2s[512];
    __shared__ float part[2048];
    __shared__ float hw[512];
    __shared__ float sc[64];
    __shared__ float wn[64];

    h2s[tid] = h2r[b * 512 + tid];
    h2s[tid + 256] = h2r[b * 512 + 256 + tid];
    __syncthreads();

    {   // GEMV: lane l owns 8 cols a=l*8.., wave w owns k-range [w*128, w*128+128)
        float s8[8] = {};
        const bf16_t* wp = W2tb + l * 8;
        for (int k = w * 128; k < w * 128 + 128; ++k) {
            float h = h2s[k];
            bf16x8 w8 = *(const bf16x8*)&wp[(size_t)k * 512];
#pragma unroll
            for (int i = 0; i < 8; ++i) s8[i] += h * (float)w8[i];
        }
#pragma unroll
        for (int i = 0; i < 8; ++i) part[(l * 8 + i) * 4 + w] = s8[i];
    }
    __syncthreads();
#pragma unroll
    for (int r = 0; r < 2; ++r) {
        int a = tid + r * 256;
        hw[a] = b2[a] + part[a * 4] + part[a * 4 + 1] + part[a * 4 + 2] + part[a * 4 + 3];
    }
    __syncthreads();
    {   // scores
        float hwr[8], Vr[8];
#pragma unroll
        for (int i = 0; i < 8; ++i) { hwr[i] = hw[l * 8 + i]; Vr[i] = V[l * 8 + i]; }
        for (int pq = w; pq < P_; pq += 4) {
            bf16x8 f8 = *(const bf16x8*)&fW1b[(size_t)(b * P_ + pq) * 512 + l * 8];
            float s = 0.f;
#pragma unroll
            for (int i = 0; i < 8; ++i) s += tanhf((float)f8[i] + hwr[i]) * Vr[i];
#pragma unroll
            for (int o = 32; o; o >>= 1) s += __shfl_xor(s, o);
            if (l == 0) sc[pq] = s + bV[0];
        }
    }
    __syncthreads();
    {
        float m = -1e30f;
        for (int q = 0; q < P_; ++q) m = fmaxf(m, sc[q]);
        float ss = 0.f;
        for (int q = 0; q < P_; ++q) ss += expf(sc[q] - m);
        if (tid < P_) wn[tid] = expf(sc[tid] - m) / ss;
    }
    __syncthreads();
    {   // ctx
        float acc[8] = {};
        const bf16_t* fb = featb + (size_t)b * P_ * 2048 + tid * 8;
        for (int q = 0; q < P_; ++q) {
            bf16x8 f8 = *(const bf16x8*)&fb[(size_t)q * 2048];
            float wq = wn[q];
#pragma unroll
            for (int i = 0; i < 8; ++i) acc[i] += wq * (float)f8[i];
        }
        bf16x8 o8;
#pragma unroll
        for (int i = 0; i < 8; ++i) o8[i] = (bf16_t)acc[i];
        *(bf16x8*)&ctxb[b * 2048 + tid * 8] = o8;
    }
}

// ---------------------------------------------------------------------------
// Per-step kernel 2: gates1 + pw1. 32 blocks x 256 thr, no LDS.
// Block nb owns d-strip nb*16..+15; accs = gate cols {d,512+d,1024+d,1536+d};
// C-frag layout puts gi,gf,gg,go for (b,d) in the same thread -> pw1 in regs.
// All state per-t write-once: reads ctxb + h1 slice t + c1 slice (t&1);
// writes h1 slice t+1 + c1 slice ((t+1)&1).
// ---------------------------------------------------------------------------
__global__ __launch_bounds__(256) void g1pw_k(
    const bf16_t* __restrict__ ctxb, const bf16_t* __restrict__ h1r,
    const bf16_t* __restrict__ fp1,  const bf16_t* __restrict__ xeb,
    const float* __restrict__ c1r,   float* __restrict__ c1w,
    bf16_t* __restrict__ h1w)
{
    const int nb = blockIdx.x, tid = threadIdx.x;
    const int w = tid >> 6, l = tid & 63;
    const int arow = w * 16 + (l & 15);
    const int koff = (l >> 4) * 8;
    f32x4 acc[4] = {};
    const bf16_t* wp = fp1 + (size_t)nb * 80 * 2048 + l * 8;
    {   // ctx part: kf 0..63
        const bf16_t* ap = ctxb + arow * 2048 + koff;
        for (int kf = 0; kf < 64; ++kf) {
            bf16x8 a8 = *(const bf16x8*)&ap[kf * 32];
            const bf16_t* wk = wp + (size_t)kf * 2048;
#pragma unroll
            for (int s = 0; s < 4; ++s) {
                bf16x8 w8 = *(const bf16x8*)&wk[s * 512];
                acc[s] = __builtin_amdgcn_mfma_f32_16x16x32_bf16(a8, w8, acc[s], 0, 0, 0);
            }
        }
    }
    {   // h1 part: kf 64..79
        const bf16_t* ap = h1r + arow * 512 + koff;
        for (int kf = 0; kf < 16; ++kf) {
            bf16x8 a8 = *(const bf16x8*)&ap[kf * 32];
            const bf16_t* wk = wp + (size_t)(64 + kf) * 2048;
#pragma unroll
            for (int s = 0; s < 4; ++s) {
                bf16x8 w8 = *(const bf16x8*)&wk[s * 512];
                acc[s] = __builtin_amdgcn_mfma_f32_16x16x32_bf16(a8, w8, acc[s], 0, 0, 0);
            }
        }
    }
    const int rb = w * 16 + ((l >> 4) << 2);
    const int d = nb * 16 + (l & 15);
#pragma unroll
    for (int j = 0; j < 4; ++j) {
        int row = rb + j;
        float gi = acc[0][j] + (float)xeb[row * 2048 + d];
        float gf = acc[1][j] + (float)xeb[row * 2048 + 512 + d];
        float gg = acc[2][j] + (float)xeb[row * 2048 + 1024 + d];
        float go = acc[3][j] + (float)xeb[row * 2048 + 1536 + d];
        float cn = sigf(gf) * c1r[row * 512 + d] + sigf(gi) * tanhf(gg);
        c1w[row * 512 + d] = cn;
        h1w[row * 512 + d] = (bf16_t)(sigf(go) * tanhf(cn));
    }
}

// ---------------------------------------------------------------------------
// Per-step kernel 3: gates2 + pw2. 32 blocks x 256 thr.
// Reads h1 slice t+1 + h2 slice t + c2 slice (t&1);
// writes h2 slice t+1 (bf16, = fc input row block) + h2f32 slice t+1 +
// c2 slice ((t+1)&1). All write-once per call.
// ---------------------------------------------------------------------------
__global__ __launch_bounds__(256) void g2pw_k(
    const bf16_t* __restrict__ h1n, const bf16_t* __restrict__ h2r,
    const bf16_t* __restrict__ fp2, const float* __restrict__ bsum2,
    const float* __restrict__ c2r,  float* __restrict__ c2w,
    bf16_t* __restrict__ h2w, float* __restrict__ h2fw)
{
    const int nb = blockIdx.x, tid = threadIdx.x;
    const int w = tid >> 6, l = tid & 63;
    const int arow = w * 16 + (l & 15);
    const int koff = (l >> 4) * 8;
    f32x4 acc[4] = {};
    const bf16_t* wp = fp2 + (size_t)nb * 32 * 2048 + l * 8;
    {   // h1 part: kf 0..15
        const bf16_t* ap = h1n + arow * 512 + koff;
        for (int kf = 0; kf < 16; ++kf) {
            bf16x8 a8 = *(const bf16x8*)&ap[kf * 32];
            const bf16_t* wk = wp + (size_t)kf * 2048;
#pragma unroll
            for (int s = 0; s < 4; ++s) {
                bf16x8 w8 = *(const bf16x8*)&wk[s * 512];
                acc[s] = __builtin_amdgcn_mfma_f32_16x16x32_bf16(a8, w8, acc[s], 0, 0, 0);
            }
        }
    }
    {   // h2 part: kf 16..31
        const bf16_t* ap = h2r + arow * 512 + koff;
        for (int kf = 0; kf < 16; ++kf) {
            bf16x8 a8 = *(const bf16x8*)&ap[kf * 32];
            const bf16_t* wk = wp + (size_t)(16 + kf) * 2048;
#pragma unroll
            for (int s = 0; s < 4; ++s) {
                bf16x8 w8 = *(const bf16x8*)&wk[s * 512];
                acc[s] = __builtin_amdgcn_mfma_f32_16x16x32_bf16(a8, w8, acc[s], 0, 0, 0);
            }
        }
    }
    const int rb = w * 16 + ((l >> 4) << 2);
    const int d = nb * 16 + (l & 15);
#pragma unroll
    for (int j = 0; j < 4; ++j) {
        int row = rb + j;
        float gi = acc[0][j] + bsum2[d];
        float gf = acc[1][j] + bsum2[512 + d];
        float gg = acc[2][j] + bsum2[1024 + d];
        float go = acc[3][j] + bsum2[1536 + d];
        float cn = sigf(gf) * c2r[row * 512 + d] + sigf(gi) * tanhf(gg);
        c2w[row * 512 + d] = cn;
        float h = sigf(go) * tanhf(cn);
        h2w[row * 512 + d] = (bf16_t)h;
        h2fw[row * 512 + d] = h;
    }
}

// ---------------------------------------------------------------------------
extern "C" void kernel_launch(void* const* d_in, const int* in_sizes, int n_in,
                              void* d_out, int out_size, void* d_ws, size_t ws_size,
                              hipStream_t stream)
{
    const float* features = (const float*)d_in[0];
    const int*   captions = (const int*)d_in[1];
    const float* emb   = (const float*)d_in[2];
    const float* W1    = (const float*)d_in[3];
    const float* b1    = (const float*)d_in[4];
    const float* W2    = (const float*)d_in[5];
    const float* b2    = (const float*)d_in[6];
    const float* V     = (const float*)d_in[7];
    const float* bV    = (const float*)d_in[8];
    const float* W_ih1 = (const float*)d_in[9];
    const float* W_hh1 = (const float*)d_in[10];
    const float* b_ih1 = (const float*)d_in[11];
    const float* b_hh1 = (const float*)d_in[12];
    const float* W_ih2 = (const float*)d_in[13];
    const float* W_hh2 = (const float*)d_in[14];
    const float* b_ih2 = (const float*)d_in[15];
    const float* b_hh2 = (const float*)d_in[16];
    const float* fc_W  = (const float*)d_in[17];
    const float* fc_b  = (const float*)d_in[18];
    float* out = (float*)d_out;

    char* ws = (char*)d_ws;
    size_t off = 0;
    auto alloc = [&](size_t nbytes) {
        char* pp = ws + off;
        off = (off + nbytes + 255) & ~(size_t)255;
        return pp;
    };
    bf16_t* featb  = (bf16_t*)alloc(3136L * 2048 * 2);   // 12.8 MB
    bf16_t* fW1b   = (bf16_t*)alloc(3136L * 512 * 2);    // 3.2 MB
    bf16_t* W1b    = (bf16_t*)alloc(512L * 2048 * 2);
    bf16_t* W2tb   = (bf16_t*)alloc(512L * 512 * 2);
    bf16_t* Wihel  = (bf16_t*)alloc(2048L * 256 * 2);
    bf16_t* fp1    = (bf16_t*)alloc(2048L * 2560 * 2);   // 10.5 MB
    bf16_t* fp2    = (bf16_t*)alloc(2048L * 1024 * 2);   // 4.2 MB
    bf16_t* fcWb   = (bf16_t*)alloc((size_t)VPAD * 512 * 2);  // 10.3 MB
    bf16_t* xgb    = (bf16_t*)alloc(1920L * 256 * 2);
    bf16_t* xembb  = (bf16_t*)alloc(1920L * 2048 * 2);   // 7.9 MB (bf16 now)
    float*  bsum1  = (float*)alloc(2048 * 4);
    float*  bsum2  = (float*)alloc(2048 * 4);
    bf16_t* ctxb   = (bf16_t*)alloc((size_t)B_ * ENC * 2);
    // per-timestep write-once state
    bf16_t* h1s    = (bf16_t*)alloc((size_t)(T_ + 1) * B_ * DEC * 2);  // 2.0 MB
    bf16_t* h2s    = (bf16_t*)alloc((size_t)(T_ + 1) * B_ * DEC * 2);  // 2.0 MB
    float*  h2f32  = (float*)alloc((size_t)(T_ + 1) * B_ * DEC * 4);   // 4.1 MB
    float*  c1s    = (float*)alloc(2L * B_ * DEC * 4);
    float*  c2s    = (float*)alloc(2L * B_ * DEC * 4);
    // total ~62.7 MB (< proven 68.5 MB)

    zero_k<<<256, 256, 0, stream>>>(h1s, h2s, h2f32, c1s, c2s);

    prep_k<<<4096, 256, 0, stream>>>(
        b_ih1, b_hh1, bsum1, b_ih2, b_hh2, bsum2,
        W2, W2tb, W1, W1b, W_ih1, Wihel, fp1,
        W_ih2, W_hh1, W_hh2, fp2, fc_W, fcWb,
        features, featb, captions, emb, xgb);

    // fW1b = features @ W1^T + b1  (bf16 out)
    mm_bf16<0><<<dim3(ATT / 64, (B_ * P_) / 64), 256, 0, stream>>>(
        featb, ENC, W1b, ENC, b1, nullptr, fW1b, ATT, ATT, ENC);
    // xembb = xg @ Wih1[:, :256]^T + (b_ih1+b_hh1)  (bf16 out)
    mm_bf16<0><<<dim3(G4 / 64, (T_ * B_) / 64), 256, 0, stream>>>(
        xgb, EMBED, Wihel, EMBED, bsum1, nullptr, xembb, G4, G4, EMBED);

    const int SL = B_ * DEC;  // 32768, one state slice
    for (int t = 0; t < T_; ++t) {
        attn_k<<<B_, 256, 0, stream>>>(
            h2f32 + (size_t)t * SL, W2tb, b2, fW1b, V, bV, featb, ctxb);
        g1pw_k<<<32, 256, 0, stream>>>(
            ctxb, h1s + (size_t)t * SL, fp1, xembb + (size_t)t * B_ * G4,
            c1s + (size_t)(t & 1) * SL, c1s + (size_t)((t + 1) & 1) * SL,
            h1s + (size_t)(t + 1) * SL);
        g2pw_k<<<32, 256, 0, stream>>>(
            h1s + (size_t)(t + 1) * SL, h2s + (size_t)t * SL, fp2, bsum2,
            c2s + (size_t)(t & 1) * SL, c2s + (size_t)((t + 1) & 1) * SL,
            h2s + (size_t)(t + 1) * SL, h2f32 + (size_t)(t + 1) * SL);
    }

    // out = h2(1..30) @ fc_W^T + fc_b  (f32 out, row remap t*64+b -> b*T+t)
    mm_bf16<2><<<dim3(VPAD / 64, (T_ * B_) / 64), 256, 0, stream>>>(
        h2s + SL, DEC, fcWb, DEC, fc_b, out, nullptr, VOCAB, VOCAB, DEC);
}

// Round 7
// 1558.322 us; speedup vs baseline: 3.4480x; 1.7324x over previous
//
#include <hip/hip_runtime.h>
#include <math.h>

#define VOCAB 10000
#define VPAD  10240   // padded to 160 n-tiles so bid%8 (XCD) is stable per n-tile
#define EMBED 256
#define ENC   2048
#define DEC   512
#define ATT   512
#define B_    64
#define P_    49
#define T_    30
#define G4    2048   // 4*DEC
#define KH1   10     // g1 K-chunks: 8 over ctx (K=2048) + 2 over h1 (K=512)

typedef __bf16 bf16_t;
typedef bf16_t bf16x8 __attribute__((ext_vector_type(8)));
typedef float  f32x4  __attribute__((ext_vector_type(4)));

__device__ __forceinline__ float sigf(float x) { return 1.f / (1.f + expf(-x)); }

// ---------------------------------------------------------------------------
// Per-call state init (write-once state discipline from round 6 — keep).
// ---------------------------------------------------------------------------
__global__ void zero_k(bf16_t* __restrict__ h1s0, bf16_t* __restrict__ h2s0,
                       float* __restrict__ c1s, float* __restrict__ c2s)
{
    int i = blockIdx.x * 256 + threadIdx.x;           // 65536 threads
    if (i < 32768) { h1s0[i] = (bf16_t)0.f; h2s0[i] = (bf16_t)0.f; }
    c1s[i] = 0.f;
    c2s[i] = 0.f;
}

// ---------------------------------------------------------------------------
// One-time prep. Fragment packings (verified rounds 5/6):
// fp1[((nb*80+kf)*4+s)*512 + l*8 + j] = Wcat1[s*512+nb*16+(l&15)][kf*32+(l>>4)*8+j]
// fp2 same with 32 kf, Wcat2.
// W2p[(nt*16+kf)*512 + l*8 + j]      = W2[nt*16+(l&15)][kf*32+(l>>4)*8+j]
// ---------------------------------------------------------------------------
__global__ void prep_k(
    const float* __restrict__ b_ih1, const float* __restrict__ b_hh1, float* __restrict__ bsum1,
    const float* __restrict__ b_ih2, const float* __restrict__ b_hh2, float* __restrict__ bsum2,
    const float* __restrict__ W2,    bf16_t* __restrict__ W2p,
    const float* __restrict__ W1,    bf16_t* __restrict__ W1b,
    const float* __restrict__ W_ih1, bf16_t* __restrict__ Wihel, bf16_t* __restrict__ fp1,
    const float* __restrict__ W_ih2, const float* __restrict__ W_hh1,
    const float* __restrict__ W_hh2, bf16_t* __restrict__ fp2,
    const float* __restrict__ fc_W,  bf16_t* __restrict__ fcWb,
    const float* __restrict__ features, bf16_t* __restrict__ featb,
    const int* __restrict__ caps, const float* __restrict__ emb, bf16_t* __restrict__ xgb)
{
    long stride = (long)gridDim.x * blockDim.x;
    long i0 = (long)blockIdx.x * blockDim.x + threadIdx.x;
    for (long i = i0; i < 2048; i += stride) {
        bsum1[i] = b_ih1[i] + b_hh1[i];
        bsum2[i] = b_ih2[i] + b_hh2[i];
    }
    for (long i = i0; i < 512L * 512; i += stride) {   // W2p fragment pack
        long j8 = i & 7, lq = (i >> 3) & 63, kf = (i >> 9) & 15, nt = i >> 13;
        W2p[i] = (bf16_t)W2[(nt * 16 + (lq & 15)) * 512 + kf * 32 + (lq >> 4) * 8 + j8];
    }
    for (long i = i0; i < 512L * 2048; i += stride) W1b[i] = (bf16_t)W1[i];
    for (long i = i0; i < 2048L * 256; i += stride) {
        long j = i >> 8, c = i & 255;
        Wihel[i] = (bf16_t)W_ih1[j * 2304 + c];
    }
    for (long i = i0; i < 2048L * 2560; i += stride) { // fp1
        long j8 = i & 7, lq = (i >> 3) & 63, s = (i >> 9) & 3, nk = i >> 11;
        long kf = nk % 80, nb = nk / 80;
        long c = s * 512 + nb * 16 + (lq & 15);
        long k = kf * 32 + (lq >> 4) * 8 + j8;
        fp1[i] = (bf16_t)(k < 2048 ? W_ih1[c * 2304 + 256 + k] : W_hh1[c * 512 + (k - 2048)]);
    }
    for (long i = i0; i < 2048L * 1024; i += stride) { // fp2
        long j8 = i & 7, lq = (i >> 3) & 63, s = (i >> 9) & 3, nk = i >> 11;
        long kf = nk & 31, nb = nk >> 5;
        long c = s * 512 + nb * 16 + (lq & 15);
        long k = kf * 32 + (lq >> 4) * 8 + j8;
        fp2[i] = (bf16_t)(k < 512 ? W_ih2[c * 512 + k] : W_hh2[c * 512 + (k - 512)]);
    }
    for (long i = i0; i < (long)VPAD * 512; i += stride) {
        long r = i >> 9;
        fcWb[i] = (bf16_t)(r < VOCAB ? fc_W[i] : 0.f);
    }
    for (long i = i0; i < 3136L * 2048; i += stride) featb[i] = (bf16_t)features[i];
    for (long i = i0; i < 1920L * 256; i += stride) {
        long row = i >> 8, e = i & 255;
        long tq = row >> 6, b = row & 63;
        int cap = caps[b * T_ + tq];
        xgb[i] = (bf16_t)emb[(long)cap * 256 + e];
    }
}

// ---------------------------------------------------------------------------
// bf16 MFMA GEMM (bulk GEMMs): C[M,N] = A[M,K] @ W[N,K]^T + bias[N].
// MODE 0: bf16 out. MODE 2: f32 out, fc row-remap + N guard. (Verified r2/r6.)
// ---------------------------------------------------------------------------
template <int MODE>
__global__ __launch_bounds__(256) void mm_bf16(
    const bf16_t* __restrict__ A, int lda,
    const bf16_t* __restrict__ Bw, int ldb,
    const float* __restrict__ bias,
    float* __restrict__ outF, bf16_t* __restrict__ outB, int ldo,
    int N, int K)
{
    __shared__ bf16_t Apad[64][72];
    __shared__ bf16_t Bpad[64][72];
    const int bn = blockIdx.x * 64, bm = blockIdx.y * 64;
    const int tid = threadIdx.x;
    const int w = tid >> 6, l = tid & 63;
    f32x4 acc[4] = {};

    for (int k0 = 0; k0 < K; k0 += 64) {
        for (int c = tid; c < 512; c += 256) {
            int row = c >> 3, q = c & 7;
            *(bf16x8*)&Apad[row][q * 8] = *(const bf16x8*)&A[(size_t)(bm + row) * lda + k0 + q * 8];
            *(bf16x8*)&Bpad[row][q * 8] = *(const bf16x8*)&Bw[(size_t)(bn + row) * ldb + k0 + q * 8];
        }
        __syncthreads();
#pragma unroll
        for (int ks = 0; ks < 2; ++ks) {
            bf16x8 a8 = *(const bf16x8*)&Apad[w * 16 + (l & 15)][ks * 32 + (l >> 4) * 8];
#pragma unroll
            for (int nf = 0; nf < 4; ++nf) {
                bf16x8 b8 = *(const bf16x8*)&Bpad[nf * 16 + (l & 15)][ks * 32 + (l >> 4) * 8];
                acc[nf] = __builtin_amdgcn_mfma_f32_16x16x32_bf16(a8, b8, acc[nf], 0, 0, 0);
            }
        }
        __syncthreads();
    }

    int rbase = bm + w * 16 + (l >> 4) * 4;
    int cl = l & 15;
#pragma unroll
    for (int nf = 0; nf < 4; ++nf) {
        int col = bn + nf * 16 + cl;
#pragma unroll
        for (int j = 0; j < 4; ++j) {
            int row = rbase + j;
            float v = acc[nf][j];
            if (MODE == 0) {
                outB[(size_t)row * ldo + col] = (bf16_t)(v + bias[col]);
            } else {
                if (col < N) {
                    int orow = (row & 63) * T_ + (row >> 6);  // t*64+b -> b*T+t
                    outF[(size_t)orow * ldo + col] = v + bias[col];
                }
            }
        }
    }
}

// ---------------------------------------------------------------------------
// Step kernel 0: hw = h2 @ W2^T + b2, M=64 N=512 K=512. 32 blocks x 256 thr.
// W2 is read ONCE per step (vs 64x in round 6's per-batch GEMV: -31.5 MB/step).
// ---------------------------------------------------------------------------
__global__ __launch_bounds__(256) void hw_k(
    const bf16_t* __restrict__ h2r, const bf16_t* __restrict__ W2p,
    const float* __restrict__ b2, float* __restrict__ hwb)
{
    const int nt = blockIdx.x, tid = threadIdx.x;
    const int w = tid >> 6, l = tid & 63;
    const bf16_t* ap = h2r + (w * 16 + (l & 15)) * 512 + (l >> 4) * 8;
    const bf16_t* wp = W2p + (size_t)nt * 16 * 512 + l * 8;
    f32x4 acc = {};
#pragma unroll
    for (int kf = 0; kf < 16; ++kf) {
        bf16x8 a8 = *(const bf16x8*)&ap[kf * 32];
        bf16x8 w8 = *(const bf16x8*)&wp[(size_t)kf * 512];
        acc = __builtin_amdgcn_mfma_f32_16x16x32_bf16(a8, w8, acc, 0, 0, 0);
    }
    const int row = w * 16 + (l >> 4) * 4;
    const int col = nt * 16 + (l & 15);
#pragma unroll
    for (int j = 0; j < 4; ++j)
        hwb[(row + j) * 512 + col] = acc[j] + b2[col];
}

// ---------------------------------------------------------------------------
// Step kernel 1: attention scores + softmax + ctx. 64 blocks x 256 thr.
// (round-6 attn minus the W2 GEMV; hw row read from hwb.)
// ---------------------------------------------------------------------------
__global__ __launch_bounds__(256) void attn_k(
    const float* __restrict__ hwb, const bf16_t* __restrict__ fW1b,
    const float* __restrict__ V, const float* __restrict__ bV,
    const bf16_t* __restrict__ featb, bf16_t* __restrict__ ctxb)
{
    const int b = blockIdx.x, tid = threadIdx.x;
    const int w = tid >> 6, l = tid & 63;
    __shared__ float sc[64];
    __shared__ float wn[64];

    {   // scores
        float hwr[8], Vr[8];
#pragma unroll
        for (int i = 0; i < 8; ++i) { hwr[i] = hwb[b * 512 + l * 8 + i]; Vr[i] = V[l * 8 + i]; }
        for (int pq = w; pq < P_; pq += 4) {
            bf16x8 f8 = *(const bf16x8*)&fW1b[(size_t)(b * P_ + pq) * 512 + l * 8];
            float s = 0.f;
#pragma unroll
            for (int i = 0; i < 8; ++i) s += tanhf((float)f8[i] + hwr[i]) * Vr[i];
#pragma unroll
            for (int o = 32; o; o >>= 1) s += __shfl_xor(s, o);
            if (l == 0) sc[pq] = s + bV[0];
        }
    }
    __syncthreads();
    {
        float m = -1e30f;
        for (int q = 0; q < P_; ++q) m = fmaxf(m, sc[q]);
        float ss = 0.f;
        for (int q = 0; q < P_; ++q) ss += expf(sc[q] - m);
        if (tid < P_) wn[tid] = expf(sc[tid] - m) / ss;
    }
    __syncthreads();
    {   // ctx
        float acc[8] = {};
        const bf16_t* fb = featb + (size_t)b * P_ * 2048 + tid * 8;
#pragma unroll 7
        for (int q = 0; q < P_; ++q) {
            bf16x8 f8 = *(const bf16x8*)&fb[(size_t)q * 2048];
            float wq = wn[q];
#pragma unroll
            for (int i = 0; i < 8; ++i) acc[i] += wq * (float)f8[i];
        }
        bf16x8 o8;
#pragma unroll
        for (int i = 0; i < 8; ++i) o8[i] = (bf16_t)acc[i];
        *(bf16x8*)&ctxb[b * 2048 + tid * 8] = o8;
    }
}

// ---------------------------------------------------------------------------
// Step kernel 2: gates1 partials. grid (32 d-strips, 10 K-chunks) = 320 blocks
// -> whole chip streams fp1 (32 KB/block). Partials G1p[kh][64][2048] f32.
// kh<8: ctx K-chunk kh*256; kh 8/9: h1 K-chunk (kh-8)*256.
// ---------------------------------------------------------------------------
__global__ __launch_bounds__(256) void g1p_k(
    const bf16_t* __restrict__ ctxb, const bf16_t* __restrict__ h1r,
    const bf16_t* __restrict__ fp1, float* __restrict__ G1p)
{
    const int nb = blockIdx.x, kh = blockIdx.y, tid = threadIdx.x;
    const int w = tid >> 6, l = tid & 63;
    const int arow = w * 16 + (l & 15);
    const int koff = (l >> 4) * 8;
    const bf16_t* ap;
    const bf16_t* wp;
    if (kh < 8) {
        ap = ctxb + arow * 2048 + kh * 256 + koff;
        wp = fp1 + ((size_t)nb * 80 + kh * 8) * 2048 + l * 8;
    } else {
        ap = h1r + arow * 512 + (kh - 8) * 256 + koff;
        wp = fp1 + ((size_t)nb * 80 + 64 + (kh - 8) * 8) * 2048 + l * 8;
    }
    f32x4 acc[4] = {};
#pragma unroll
    for (int i = 0; i < 8; ++i) {
        bf16x8 a8 = *(const bf16x8*)&ap[i * 32];
        const bf16_t* wk = wp + (size_t)i * 2048;
#pragma unroll
        for (int s = 0; s < 4; ++s) {
            bf16x8 w8 = *(const bf16x8*)&wk[s * 512];
            acc[s] = __builtin_amdgcn_mfma_f32_16x16x32_bf16(a8, w8, acc[s], 0, 0, 0);
        }
    }
    const int rb = w * 16 + ((l >> 4) << 2);
    const int d = nb * 16 + (l & 15);
    float* gp = G1p + (size_t)kh * (64 * 2048);
#pragma unroll
    for (int s = 0; s < 4; ++s)
#pragma unroll
        for (int j = 0; j < 4; ++j)
            gp[(rb + j) * 2048 + s * 512 + d] = acc[s][j];
}

// ---------------------------------------------------------------------------
// Step kernel 3: pw1 — sum 10 partials + xembb, LSTM1 pointwise.
// 128 blocks x 256 thr, one cell per thread (coalesced partial reads).
// ---------------------------------------------------------------------------
__global__ __launch_bounds__(256) void pw1_k(
    const float* __restrict__ G1p, const bf16_t* __restrict__ xeb,
    const float* __restrict__ c1r, float* __restrict__ c1w,
    bf16_t* __restrict__ h1w)
{
    const int idx = blockIdx.x * 256 + threadIdx.x;  // 0..32767
    const int row = idx >> 9, d = idx & 511;
    float g[4];
#pragma unroll
    for (int s = 0; s < 4; ++s) g[s] = (float)xeb[row * 2048 + s * 512 + d];
#pragma unroll
    for (int kh = 0; kh < KH1; ++kh) {
        const float* gp = G1p + (size_t)kh * (64 * 2048) + row * 2048 + d;
#pragma unroll
        for (int s = 0; s < 4; ++s) g[s] += gp[s * 512];
    }
    float cn = sigf(g[1]) * c1r[idx] + sigf(g[0]) * tanhf(g[2]);
    c1w[idx] = cn;
    h1w[idx] = (bf16_t)(sigf(g[3]) * tanhf(cn));
}

// ---------------------------------------------------------------------------
// Step kernel 4: gates2 + fused pw2. 32 blocks x 512 thr (8 waves):
// wave-group wg=0 does K 0..512 (h1 new), wg=1 does K 512..1024 (h2 old);
// LDS reduce, then waves 0..3 do the register-local LSTM2 pointwise.
// Writes h2 slice t+1 (bf16: feeds hw_k, g2pw A, and the fc GEMM) + c2.
// ---------------------------------------------------------------------------
__global__ __launch_bounds__(512) void g2pw_k(
    const bf16_t* __restrict__ h1n, const bf16_t* __restrict__ h2r,
    const bf16_t* __restrict__ fp2, const float* __restrict__ bsum2,
    const float* __restrict__ c2r, float* __restrict__ c2w,
    bf16_t* __restrict__ h2w)
{
    const int nb = blockIdx.x, tid = threadIdx.x;
    const int w = tid >> 6, l = tid & 63;
    const int mt = w & 3, wg = w >> 2;
    const int arow = mt * 16 + (l & 15);
    const int koff = (l >> 4) * 8;
    __shared__ float red[2][4][4][256];  // [wg][mt][s][l*4+j] = 32 KB

    const bf16_t* ap = (wg == 0 ? h1n : h2r) + arow * 512 + koff;
    const bf16_t* wp = fp2 + ((size_t)nb * 32 + wg * 16) * 2048 + l * 8;
    f32x4 acc[4] = {};
#pragma unroll
    for (int kf = 0; kf < 16; ++kf) {
        bf16x8 a8 = *(const bf16x8*)&ap[kf * 32];
        const bf16_t* wk = wp + (size_t)kf * 2048;
#pragma unroll
        for (int s = 0; s < 4; ++s) {
            bf16x8 w8 = *(const bf16x8*)&wk[s * 512];
            acc[s] = __builtin_amdgcn_mfma_f32_16x16x32_bf16(a8, w8, acc[s], 0, 0, 0);
        }
    }
#pragma unroll
    for (int s = 0; s < 4; ++s) *(f32x4*)&red[wg][mt][s][l * 4] = acc[s];
    __syncthreads();

    if (w < 4) {
        const int d = nb * 16 + (l & 15);
        const int rb = w * 16 + ((l >> 4) << 2);
        f32x4 v[4];
#pragma unroll
        for (int s = 0; s < 4; ++s)
            v[s] = *(const f32x4*)&red[0][w][s][l * 4] + *(const f32x4*)&red[1][w][s][l * 4];
#pragma unroll
        for (int j = 0; j < 4; ++j) {
            int row = rb + j;
            float gi = v[0][j] + bsum2[d];
            float gf = v[1][j] + bsum2[512 + d];
            float gg = v[2][j] + bsum2[1024 + d];
            float go = v[3][j] + bsum2[1536 + d];
            float cn = sigf(gf) * c2r[row * 512 + d] + sigf(gi) * tanhf(gg);
            c2w[row * 512 + d] = cn;
            h2w[row * 512 + d] = (bf16_t)(sigf(go) * tanhf(cn));
        }
    }
}

// ---------------------------------------------------------------------------
extern "C" void kernel_launch(void* const* d_in, const int* in_sizes, int n_in,
                              void* d_out, int out_size, void* d_ws, size_t ws_size,
                              hipStream_t stream)
{
    const float* features = (const float*)d_in[0];
    const int*   captions = (const int*)d_in[1];
    const float* emb   = (const float*)d_in[2];
    const float* W1    = (const float*)d_in[3];
    const float* b1    = (const float*)d_in[4];
    const float* W2    = (const float*)d_in[5];
    const float* b2    = (const float*)d_in[6];
    const float* V     = (const float*)d_in[7];
    const float* bV    = (const float*)d_in[8];
    const float* W_ih1 = (const float*)d_in[9];
    const float* W_hh1 = (const float*)d_in[10];
    const float* b_ih1 = (const float*)d_in[11];
    const float* b_hh1 = (const float*)d_in[12];
    const float* W_ih2 = (const float*)d_in[13];
    const float* W_hh2 = (const float*)d_in[14];
    const float* b_ih2 = (const float*)d_in[15];
    const float* b_hh2 = (const float*)d_in[16];
    const float* fc_W  = (const float*)d_in[17];
    const float* fc_b  = (const float*)d_in[18];
    float* out = (float*)d_out;

    char* ws = (char*)d_ws;
    size_t off = 0;
    auto alloc = [&](size_t nbytes) {
        char* pp = ws + off;
        off = (off + nbytes + 255) & ~(size_t)255;
        return pp;
    };
    bf16_t* featb  = (bf16_t*)alloc(3136L * 2048 * 2);   // 12.8 MB
    bf16_t* fW1b   = (bf16_t*)alloc(3136L * 512 * 2);    // 3.2 MB
    bf16_t* W1b    = (bf16_t*)alloc(512L * 2048 * 2);
    bf16_t* W2p    = (bf16_t*)alloc(512L * 512 * 2);
    bf16_t* Wihel  = (bf16_t*)alloc(2048L * 256 * 2);
    bf16_t* fp1    = (bf16_t*)alloc(2048L * 2560 * 2);   // 10.5 MB
    bf16_t* fp2    = (bf16_t*)alloc(2048L * 1024 * 2);   // 4.2 MB
    bf16_t* fcWb   = (bf16_t*)alloc((size_t)VPAD * 512 * 2);  // 10.5 MB
    bf16_t* xgb    = (bf16_t*)alloc(1920L * 256 * 2);
    bf16_t* xembb  = (bf16_t*)alloc(1920L * 2048 * 2);   // 7.9 MB
    float*  bsum1  = (float*)alloc(2048 * 4);
    float*  bsum2  = (float*)alloc(2048 * 4);
    bf16_t* ctxb   = (bf16_t*)alloc((size_t)B_ * ENC * 2);
    float*  hwb    = (float*)alloc((size_t)B_ * ATT * 4);
    float*  G1p    = (float*)alloc((size_t)KH1 * B_ * G4 * 4);  // 5.2 MB
    // per-timestep write-once state
    bf16_t* h1s    = (bf16_t*)alloc((size_t)(T_ + 1) * B_ * DEC * 2);
    bf16_t* h2s    = (bf16_t*)alloc((size_t)(T_ + 1) * B_ * DEC * 2);
    float*  c1s    = (float*)alloc(2L * B_ * DEC * 4);
    float*  c2s    = (float*)alloc(2L * B_ * DEC * 4);
    // total ~64 MB (< proven 68.5 MB)

    zero_k<<<256, 256, 0, stream>>>(h1s, h2s, c1s, c2s);

    prep_k<<<4096, 256, 0, stream>>>(
        b_ih1, b_hh1, bsum1, b_ih2, b_hh2, bsum2,
        W2, W2p, W1, W1b, W_ih1, Wihel, fp1,
        W_ih2, W_hh1, W_hh2, fp2, fc_W, fcWb,
        features, featb, captions, emb, xgb);

    // fW1b = features @ W1^T + b1  (bf16 out)
    mm_bf16<0><<<dim3(ATT / 64, (B_ * P_) / 64), 256, 0, stream>>>(
        featb, ENC, W1b, ENC, b1, nullptr, fW1b, ATT, ATT, ENC);
    // xembb = xg @ Wih1[:, :256]^T + (b_ih1+b_hh1)  (bf16 out)
    mm_bf16<0><<<dim3(G4 / 64, (T_ * B_) / 64), 256, 0, stream>>>(
        xgb, EMBED, Wihel, EMBED, bsum1, nullptr, xembb, G4, G4, EMBED);

    const int SL = B_ * DEC;  // 32768, one state slice
    for (int t = 0; t < T_; ++t) {
        hw_k<<<32, 256, 0, stream>>>(h2s + (size_t)t * SL, W2p, b2, hwb);
        attn_k<<<B_, 256, 0, stream>>>(hwb, fW1b, V, bV, featb, ctxb);
        g1p_k<<<dim3(32, KH1), 256, 0, stream>>>(
            ctxb, h1s + (size_t)t * SL, fp1, G1p);
        pw1_k<<<128, 256, 0, stream>>>(
            G1p, xembb + (size_t)t * B_ * G4,
            c1s + (size_t)(t & 1) * SL, c1s + (size_t)((t + 1) & 1) * SL,
            h1s + (size_t)(t + 1) * SL);
        g2pw_k<<<32, 512, 0, stream>>>(
            h1s + (size_t)(t + 1) * SL, h2s + (size_t)t * SL, fp2, bsum2,
            c2s + (size_t)(t & 1) * SL, c2s + (size_t)((t + 1) & 1) * SL,
            h2s + (size_t)(t + 1) * SL);
    }

    // out = h2(1..30) @ fc_W^T + fc_b  (f32 out, row remap t*64+b -> b*T+t)
    // grid.x = 160 (multiple of 8): n-tile -> XCD map stable -> fcWb L2-resident
    mm_bf16<2><<<dim3(VPAD / 64, (T_ * B_) / 64), 256, 0, stream>>>(
        h2s + SL, DEC, fcWb, DEC, fc_b, out, nullptr, VOCAB, VOCAB, DEC);
}

// Round 8
// 1551.381 us; speedup vs baseline: 3.4634x; 1.0045x over previous
//
#include <hip/hip_runtime.h>
#include <hip/hip_cooperative_groups.h>
#include <math.h>

namespace cg = cooperative_groups;

#define VOCAB 10000
#define VPAD  10240   // padded so fc n-tile -> XCD map is stable (bid%8)
#define EMBED 256
#define ENC   2048
#define DEC   512
#define ATT   512
#define B_    64
#define P_    49
#define T_    30
#define G4    2048   // 4*DEC
#define KH1   10     // fallback g1 split-K chunks
#define SL    32768  // one state slice = B_*DEC

typedef __bf16 bf16_t;
typedef bf16_t bf16x8 __attribute__((ext_vector_type(8)));
typedef float  f32x4  __attribute__((ext_vector_type(4)));

__device__ __forceinline__ float sigf(float x) { return 1.f / (1.f + expf(-x)); }

// ---------------------------------------------------------------------------
// One-time prep (+ state-slice zeroing, absorbing the old zero_k node).
// Fragment packings verified rounds 5-7:
// fp1[((nb*80+kf)*4+s)*512+l*8+j] = Wcat1[s*512+nb*16+(l&15)][kf*32+(l>>4)*8+j]
// fp2 same with 32 kf (kf<16: Wih2, kf>=16: Whh2). W2p: 16-col strips of W2.
// ---------------------------------------------------------------------------
__global__ void prep_k(
    const float* __restrict__ b_ih1, const float* __restrict__ b_hh1, float* __restrict__ bsum1,
    const float* __restrict__ b_ih2, const float* __restrict__ b_hh2, float* __restrict__ bsum2,
    const float* __restrict__ W2,    bf16_t* __restrict__ W2p,
    const float* __restrict__ W1,    bf16_t* __restrict__ W1b,
    const float* __restrict__ W_ih1, bf16_t* __restrict__ Wihel, bf16_t* __restrict__ fp1,
    const float* __restrict__ W_ih2, const float* __restrict__ W_hh1,
    const float* __restrict__ W_hh2, bf16_t* __restrict__ fp2,
    const float* __restrict__ fc_W,  bf16_t* __restrict__ fcWb,
    const float* __restrict__ features, bf16_t* __restrict__ featb,
    const int* __restrict__ caps, const float* __restrict__ emb, bf16_t* __restrict__ xgb,
    bf16_t* __restrict__ h1s0, bf16_t* __restrict__ h2s0,
    float* __restrict__ c1s0, float* __restrict__ c2s0)
{
    long stride = (long)gridDim.x * blockDim.x;
    long i0 = (long)blockIdx.x * blockDim.x + threadIdx.x;
    for (long i = i0; i < SL; i += stride) {
        h1s0[i] = (bf16_t)0.f; h2s0[i] = (bf16_t)0.f;
        c1s0[i] = 0.f; c2s0[i] = 0.f;
    }
    for (long i = i0; i < 2048; i += stride) {
        bsum1[i] = b_ih1[i] + b_hh1[i];
        bsum2[i] = b_ih2[i] + b_hh2[i];
    }
    for (long i = i0; i < 512L * 512; i += stride) {   // W2p fragment pack
        long j8 = i & 7, lq = (i >> 3) & 63, kf = (i >> 9) & 15, nt = i >> 13;
        W2p[i] = (bf16_t)W2[(nt * 16 + (lq & 15)) * 512 + kf * 32 + (lq >> 4) * 8 + j8];
    }
    for (long i = i0; i < 512L * 2048; i += stride) W1b[i] = (bf16_t)W1[i];
    for (long i = i0; i < 2048L * 256; i += stride) {
        long j = i >> 8, c = i & 255;
        Wihel[i] = (bf16_t)W_ih1[j * 2304 + c];
    }
    for (long i = i0; i < 2048L * 2560; i += stride) { // fp1
        long j8 = i & 7, lq = (i >> 3) & 63, s = (i >> 9) & 3, nk = i >> 11;
        long kf = nk % 80, nb = nk / 80;
        long c = s * 512 + nb * 16 + (lq & 15);
        long k = kf * 32 + (lq >> 4) * 8 + j8;
        fp1[i] = (bf16_t)(k < 2048 ? W_ih1[c * 2304 + 256 + k] : W_hh1[c * 512 + (k - 2048)]);
    }
    for (long i = i0; i < 2048L * 1024; i += stride) { // fp2
        long j8 = i & 7, lq = (i >> 3) & 63, s = (i >> 9) & 3, nk = i >> 11;
        long kf = nk & 31, nb = nk >> 5;
        long c = s * 512 + nb * 16 + (lq & 15);
        long k = kf * 32 + (lq >> 4) * 8 + j8;
        fp2[i] = (bf16_t)(k < 512 ? W_ih2[c * 512 + k] : W_hh2[c * 512 + (k - 512)]);
    }
    for (long i = i0; i < (long)VPAD * 512; i += stride) {
        long r = i >> 9;
        fcWb[i] = (bf16_t)(r < VOCAB ? fc_W[i] : 0.f);
    }
    for (long i = i0; i < 3136L * 2048; i += stride) featb[i] = (bf16_t)features[i];
    for (long i = i0; i < 1920L * 256; i += stride) {
        long row = i >> 8, e = i & 255;
        long tq = row >> 6, b = row & 63;
        int cap = caps[b * T_ + tq];
        xgb[i] = (bf16_t)emb[(long)cap * 256 + e];
    }
}

// ---------------------------------------------------------------------------
// bf16 MFMA GEMM (bulk GEMMs) — verified r2/r6/r7.
// ---------------------------------------------------------------------------
template <int MODE>
__global__ __launch_bounds__(256) void mm_bf16(
    const bf16_t* __restrict__ A, int lda,
    const bf16_t* __restrict__ Bw, int ldb,
    const float* __restrict__ bias,
    float* __restrict__ outF, bf16_t* __restrict__ outB, int ldo,
    int N, int K)
{
    __shared__ bf16_t Apad[64][72];
    __shared__ bf16_t Bpad[64][72];
    const int bn = blockIdx.x * 64, bm = blockIdx.y * 64;
    const int tid = threadIdx.x;
    const int w = tid >> 6, l = tid & 63;
    f32x4 acc[4] = {};

    for (int k0 = 0; k0 < K; k0 += 64) {
        for (int c = tid; c < 512; c += 256) {
            int row = c >> 3, q = c & 7;
            *(bf16x8*)&Apad[row][q * 8] = *(const bf16x8*)&A[(size_t)(bm + row) * lda + k0 + q * 8];
            *(bf16x8*)&Bpad[row][q * 8] = *(const bf16x8*)&Bw[(size_t)(bn + row) * ldb + k0 + q * 8];
        }
        __syncthreads();
#pragma unroll
        for (int ks = 0; ks < 2; ++ks) {
            bf16x8 a8 = *(const bf16x8*)&Apad[w * 16 + (l & 15)][ks * 32 + (l >> 4) * 8];
#pragma unroll
            for (int nf = 0; nf < 4; ++nf) {
                bf16x8 b8 = *(const bf16x8*)&Bpad[nf * 16 + (l & 15)][ks * 32 + (l >> 4) * 8];
                acc[nf] = __builtin_amdgcn_mfma_f32_16x16x32_bf16(a8, b8, acc[nf], 0, 0, 0);
            }
        }
        __syncthreads();
    }

    int rbase = bm + w * 16 + (l >> 4) * 4;
    int cl = l & 15;
#pragma unroll
    for (int nf = 0; nf < 4; ++nf) {
        int col = bn + nf * 16 + cl;
#pragma unroll
        for (int j = 0; j < 4; ++j) {
            int row = rbase + j;
            float v = acc[nf][j];
            if (MODE == 0) {
                outB[(size_t)row * ldo + col] = (bf16_t)(v + bias[col]);
            } else {
                if (col < N) {
                    int orow = (row & 63) * T_ + (row >> 6);  // t*64+b -> b*T+t
                    outF[(size_t)orow * ldo + col] = v + bias[col];
                }
            }
        }
    }
}

// ===========================================================================
// Persistent cooperative recurrence — 256 blocks x 512 threads.
// Launch envelope mirrors r2's PROVEN-launchable config (512 thr, tiny LDS,
// modest VGPR); r3/r4's silent launch failure was in the 256-thr/56-80KB-LDS
// regime. Phase bodies are verbatim r6/r7-proven kernels.
// Per step: P0 hw (32 blk) | sync | P1 attn (64 blk) | sync |
//           P2 g1+pw1 (32 blk) | sync | P3 g2+pw2 (32 blk) | sync.
// ===========================================================================
struct PP {
    const bf16_t *featb, *fW1b, *W2p, *fp1, *fp2, *xembb;
    const float *V, *bV, *b2, *bsum2;
    bf16_t *h1s, *h2s, *ctxb;
    float *hwb, *c1s, *c2s;
};

__global__ __launch_bounds__(512, 1) void persistent_k(PP p)
{
    cg::grid_group grid = cg::this_grid();
    const int bid = blockIdx.x;
    const int tid = threadIdx.x;
    const int w = tid >> 6, l = tid & 63;
    __shared__ float sc[64];
    __shared__ float wn[64];

    for (int t = 0; t < T_; ++t) {
        const bf16_t* h2r = p.h2s + (size_t)t * SL;
        const bf16_t* h1r = p.h1s + (size_t)t * SL;
        bf16_t* h1w = p.h1s + (size_t)(t + 1) * SL;
        bf16_t* h2w = p.h2s + (size_t)(t + 1) * SL;
        const float* c1r = p.c1s + (size_t)(t & 1) * SL;
        float* c1w = p.c1s + (size_t)((t + 1) & 1) * SL;
        const float* c2r = p.c2s + (size_t)(t & 1) * SL;
        float* c2w = p.c2s + (size_t)((t + 1) & 1) * SL;

        // ---------- P0: hw = h2 @ W2^T + b2 (r7 hw_k body) ----------
        if (bid < 32 && tid < 256) {
            const int nt = bid;
            const bf16_t* ap = h2r + (w * 16 + (l & 15)) * 512 + (l >> 4) * 8;
            const bf16_t* wp = p.W2p + (size_t)nt * 16 * 512 + l * 8;
            f32x4 acc = {};
#pragma unroll
            for (int kf = 0; kf < 16; ++kf) {
                bf16x8 a8 = *(const bf16x8*)&ap[kf * 32];
                bf16x8 w8 = *(const bf16x8*)&wp[(size_t)kf * 512];
                acc = __builtin_amdgcn_mfma_f32_16x16x32_bf16(a8, w8, acc, 0, 0, 0);
            }
            const int row = w * 16 + (l >> 4) * 4;
            const int col = nt * 16 + (l & 15);
#pragma unroll
            for (int j = 0; j < 4; ++j)
                p.hwb[(row + j) * 512 + col] = acc[j] + p.b2[col];
        }
        grid.sync();

        // ---------- P1: scores + softmax + ctx (r7 attn_k body) ----------
        if (bid < 64) {
            const int b = bid;
            if (tid < 256) {
                float hwr[8], Vr[8];
#pragma unroll
                for (int i = 0; i < 8; ++i) { hwr[i] = p.hwb[b * 512 + l * 8 + i]; Vr[i] = p.V[l * 8 + i]; }
                for (int pq = w; pq < P_; pq += 4) {
                    bf16x8 f8 = *(const bf16x8*)&p.fW1b[(size_t)(b * P_ + pq) * 512 + l * 8];
                    float s = 0.f;
#pragma unroll
                    for (int i = 0; i < 8; ++i) s += tanhf((float)f8[i] + hwr[i]) * Vr[i];
#pragma unroll
                    for (int o = 32; o; o >>= 1) s += __shfl_xor(s, o);
                    if (l == 0) sc[pq] = s + p.bV[0];
                }
            }
            __syncthreads();
            {
                float m = -1e30f;
                for (int q = 0; q < P_; ++q) m = fmaxf(m, sc[q]);
                float ss = 0.f;
                for (int q = 0; q < P_; ++q) ss += expf(sc[q] - m);
                if (tid < P_) wn[tid] = expf(sc[tid] - m) / ss;
            }
            __syncthreads();
            if (tid < 256) {
                float acc[8] = {};
                const bf16_t* fb = p.featb + (size_t)b * P_ * 2048 + tid * 8;
#pragma unroll 7
                for (int q = 0; q < P_; ++q) {
                    bf16x8 f8 = *(const bf16x8*)&fb[(size_t)q * 2048];
                    float wq = wn[q];
#pragma unroll
                    for (int i = 0; i < 8; ++i) acc[i] += wq * (float)f8[i];
                }
                bf16x8 o8;
#pragma unroll
                for (int i = 0; i < 8; ++i) o8[i] = (bf16_t)acc[i];
                *(bf16x8*)&p.ctxb[b * 2048 + tid * 8] = o8;
            }
        }
        grid.sync();

        // ---------- P2: gates1 + pw1 fused (r6 g1pw_k body) ----------
        if (bid < 32 && tid < 256) {
            const int nb = bid;
            const int arow = w * 16 + (l & 15);
            const int koff = (l >> 4) * 8;
            f32x4 acc[4] = {};
            const bf16_t* wp = p.fp1 + (size_t)nb * 80 * 2048 + l * 8;
            {   // ctx part: kf 0..63
                const bf16_t* ap = p.ctxb + arow * 2048 + koff;
                for (int kf = 0; kf < 64; ++kf) {
                    bf16x8 a8 = *(const bf16x8*)&ap[kf * 32];
                    const bf16_t* wk = wp + (size_t)kf * 2048;
#pragma unroll
                    for (int s = 0; s < 4; ++s) {
                        bf16x8 w8 = *(const bf16x8*)&wk[s * 512];
                        acc[s] = __builtin_amdgcn_mfma_f32_16x16x32_bf16(a8, w8, acc[s], 0, 0, 0);
                    }
                }
            }
            {   // h1 part: kf 64..79
                const bf16_t* ap = h1r + arow * 512 + koff;
                for (int kf = 0; kf < 16; ++kf) {
                    bf16x8 a8 = *(const bf16x8*)&ap[kf * 32];
                    const bf16_t* wk = wp + (size_t)(64 + kf) * 2048;
#pragma unroll
                    for (int s = 0; s < 4; ++s) {
                        bf16x8 w8 = *(const bf16x8*)&wk[s * 512];
                        acc[s] = __builtin_amdgcn_mfma_f32_16x16x32_bf16(a8, w8, acc[s], 0, 0, 0);
                    }
                }
            }
            const int rb = w * 16 + ((l >> 4) << 2);
            const int d = nb * 16 + (l & 15);
            const bf16_t* xeb = p.xembb + (size_t)t * B_ * G4;
#pragma unroll
            for (int j = 0; j < 4; ++j) {
                int row = rb + j;
                float gi = acc[0][j] + (float)xeb[row * 2048 + d];
                float gf = acc[1][j] + (float)xeb[row * 2048 + 512 + d];
                float gg = acc[2][j] + (float)xeb[row * 2048 + 1024 + d];
                float go = acc[3][j] + (float)xeb[row * 2048 + 1536 + d];
                float cn = sigf(gf) * c1r[row * 512 + d] + sigf(gi) * tanhf(gg);
                c1w[row * 512 + d] = cn;
                h1w[row * 512 + d] = (bf16_t)(sigf(go) * tanhf(cn));
            }
        }
        grid.sync();

        // ---------- P3: gates2 + pw2 fused (r5/r7 g2pw math, full-K) ----------
        if (bid < 32 && tid < 256) {
            const int nb = bid;
            const int arow = w * 16 + (l & 15);
            const int koff = (l >> 4) * 8;
            f32x4 acc[4] = {};
            const bf16_t* wp = p.fp2 + (size_t)nb * 32 * 2048 + l * 8;
            {   // h1 part: kf 0..15
                const bf16_t* ap = h1w + arow * 512 + koff;
                for (int kf = 0; kf < 16; ++kf) {
                    bf16x8 a8 = *(const bf16x8*)&ap[kf * 32];
                    const bf16_t* wk = wp + (size_t)kf * 2048;
#pragma unroll
                    for (int s = 0; s < 4; ++s) {
                        bf16x8 w8 = *(const bf16x8*)&wk[s * 512];
                        acc[s] = __builtin_amdgcn_mfma_f32_16x16x32_bf16(a8, w8, acc[s], 0, 0, 0);
                    }
                }
            }
            {   // h2 part: kf 16..31
                const bf16_t* ap = h2r + arow * 512 + koff;
                for (int kf = 0; kf < 16; ++kf) {
                    bf16x8 a8 = *(const bf16x8*)&ap[kf * 32];
                    const bf16_t* wk = wp + (size_t)(16 + kf) * 2048;
#pragma unroll
                    for (int s = 0; s < 4; ++s) {
                        bf16x8 w8 = *(const bf16x8*)&wk[s * 512];
                        acc[s] = __builtin_amdgcn_mfma_f32_16x16x32_bf16(a8, w8, acc[s], 0, 0, 0);
                    }
                }
            }
            const int rb = w * 16 + ((l >> 4) << 2);
            const int d = nb * 16 + (l & 15);
#pragma unroll
            for (int j = 0; j < 4; ++j) {
                int row = rb + j;
                float gi = acc[0][j] + p.bsum2[d];
                float gf = acc[1][j] + p.bsum2[512 + d];
                float gg = acc[2][j] + p.bsum2[1024 + d];
                float go = acc[3][j] + p.bsum2[1536 + d];
                float cn = sigf(gf) * c2r[row * 512 + d] + sigf(gi) * tanhf(gg);
                c2w[row * 512 + d] = cn;
                h2w[row * 512 + d] = (bf16_t)(sigf(go) * tanhf(cn));
            }
        }
        grid.sync();
    }
}

// ===========================================================================
// FALLBACK path: r7's exact five per-step kernels (proven, 1558 us).
// ===========================================================================
__global__ __launch_bounds__(256) void hw_k(
    const bf16_t* __restrict__ h2r, const bf16_t* __restrict__ W2p,
    const float* __restrict__ b2, float* __restrict__ hwb)
{
    const int nt = blockIdx.x, tid = threadIdx.x;
    const int w = tid >> 6, l = tid & 63;
    const bf16_t* ap = h2r + (w * 16 + (l & 15)) * 512 + (l >> 4) * 8;
    const bf16_t* wp = W2p + (size_t)nt * 16 * 512 + l * 8;
    f32x4 acc = {};
#pragma unroll
    for (int kf = 0; kf < 16; ++kf) {
        bf16x8 a8 = *(const bf16x8*)&ap[kf * 32];
        bf16x8 w8 = *(const bf16x8*)&wp[(size_t)kf * 512];
        acc = __builtin_amdgcn_mfma_f32_16x16x32_bf16(a8, w8, acc, 0, 0, 0);
    }
    const int row = w * 16 + (l >> 4) * 4;
    const int col = nt * 16 + (l & 15);
#pragma unroll
    for (int j = 0; j < 4; ++j)
        hwb[(row + j) * 512 + col] = acc[j] + b2[col];
}

__global__ __launch_bounds__(256) void attn_k(
    const float* __restrict__ hwb, const bf16_t* __restrict__ fW1b,
    const float* __restrict__ V, const float* __restrict__ bV,
    const bf16_t* __restrict__ featb, bf16_t* __restrict__ ctxb)
{
    const int b = blockIdx.x, tid = threadIdx.x;
    const int w = tid >> 6, l = tid & 63;
    __shared__ float sc[64];
    __shared__ float wn[64];
    {
        float hwr[8], Vr[8];
#pragma unroll
        for (int i = 0; i < 8; ++i) { hwr[i] = hwb[b * 512 + l * 8 + i]; Vr[i] = V[l * 8 + i]; }
        for (int pq = w; pq < P_; pq += 4) {
            bf16x8 f8 = *(const bf16x8*)&fW1b[(size_t)(b * P_ + pq) * 512 + l * 8];
            float s = 0.f;
#pragma unroll
            for (int i = 0; i < 8; ++i) s += tanhf((float)f8[i] + hwr[i]) * Vr[i];
#pragma unroll
            for (int o = 32; o; o >>= 1) s += __shfl_xor(s, o);
            if (l == 0) sc[pq] = s + bV[0];
        }
    }
    __syncthreads();
    {
        float m = -1e30f;
        for (int q = 0; q < P_; ++q) m = fmaxf(m, sc[q]);
        float ss = 0.f;
        for (int q = 0; q < P_; ++q) ss += expf(sc[q] - m);
        if (tid < P_) wn[tid] = expf(sc[tid] - m) / ss;
    }
    __syncthreads();
    {
        float acc[8] = {};
        const bf16_t* fb = featb + (size_t)b * P_ * 2048 + tid * 8;
#pragma unroll 7
        for (int q = 0; q < P_; ++q) {
            bf16x8 f8 = *(const bf16x8*)&fb[(size_t)q * 2048];
            float wq = wn[q];
#pragma unroll
            for (int i = 0; i < 8; ++i) acc[i] += wq * (float)f8[i];
        }
        bf16x8 o8;
#pragma unroll
        for (int i = 0; i < 8; ++i) o8[i] = (bf16_t)acc[i];
        *(bf16x8*)&ctxb[b * 2048 + tid * 8] = o8;
    }
}

__global__ __launch_bounds__(256) void g1p_k(
    const bf16_t* __restrict__ ctxb, const bf16_t* __restrict__ h1r,
    const bf16_t* __restrict__ fp1, float* __restrict__ G1p)
{
    const int nb = blockIdx.x, kh = blockIdx.y, tid = threadIdx.x;
    const int w = tid >> 6, l = tid & 63;
    const int arow = w * 16 + (l & 15);
    const int koff = (l >> 4) * 8;
    const bf16_t* ap;
    const bf16_t* wp;
    if (kh < 8) {
        ap = ctxb + arow * 2048 + kh * 256 + koff;
        wp = fp1 + ((size_t)nb * 80 + kh * 8) * 2048 + l * 8;
    } else {
        ap = h1r + arow * 512 + (kh - 8) * 256 + koff;
        wp = fp1 + ((size_t)nb * 80 + 64 + (kh - 8) * 8) * 2048 + l * 8;
    }
    f32x4 acc[4] = {};
#pragma unroll
    for (int i = 0; i < 8; ++i) {
        bf16x8 a8 = *(const bf16x8*)&ap[i * 32];
        const bf16_t* wk = wp + (size_t)i * 2048;
#pragma unroll
        for (int s = 0; s < 4; ++s) {
            bf16x8 w8 = *(const bf16x8*)&wk[s * 512];
            acc[s] = __builtin_amdgcn_mfma_f32_16x16x32_bf16(a8, w8, acc[s], 0, 0, 0);
        }
    }
    const int rb = w * 16 + ((l >> 4) << 2);
    const int d = nb * 16 + (l & 15);
    float* gp = G1p + (size_t)kh * (64 * 2048);
#pragma unroll
    for (int s = 0; s < 4; ++s)
#pragma unroll
        for (int j = 0; j < 4; ++j)
            gp[(rb + j) * 2048 + s * 512 + d] = acc[s][j];
}

__global__ __launch_bounds__(256) void pw1_k(
    const float* __restrict__ G1p, const bf16_t* __restrict__ xeb,
    const float* __restrict__ c1r, float* __restrict__ c1w,
    bf16_t* __restrict__ h1w)
{
    const int idx = blockIdx.x * 256 + threadIdx.x;
    const int row = idx >> 9, d = idx & 511;
    float g[4];
#pragma unroll
    for (int s = 0; s < 4; ++s) g[s] = (float)xeb[row * 2048 + s * 512 + d];
#pragma unroll
    for (int kh = 0; kh < KH1; ++kh) {
        const float* gp = G1p + (size_t)kh * (64 * 2048) + row * 2048 + d;
#pragma unroll
        for (int s = 0; s < 4; ++s) g[s] += gp[s * 512];
    }
    float cn = sigf(g[1]) * c1r[idx] + sigf(g[0]) * tanhf(g[2]);
    c1w[idx] = cn;
    h1w[idx] = (bf16_t)(sigf(g[3]) * tanhf(cn));
}

__global__ __launch_bounds__(512) void g2pw_k(
    const bf16_t* __restrict__ h1n, const bf16_t* __restrict__ h2r,
    const bf16_t* __restrict__ fp2, const float* __restrict__ bsum2,
    const float* __restrict__ c2r, float* __restrict__ c2w,
    bf16_t* __restrict__ h2w)
{
    const int nb = blockIdx.x, tid = threadIdx.x;
    const int w = tid >> 6, l = tid & 63;
    const int mt = w & 3, wg = w >> 2;
    const int arow = mt * 16 + (l & 15);
    const int koff = (l >> 4) * 8;
    __shared__ float red[2][4][4][256];

    const bf16_t* ap = (wg == 0 ? h1n : h2r) + arow * 512 + koff;
    const bf16_t* wp = fp2 + ((size_t)nb * 32 + wg * 16) * 2048 + l * 8;
    f32x4 acc[4] = {};
#pragma unroll
    for (int kf = 0; kf < 16; ++kf) {
        bf16x8 a8 = *(const bf16x8*)&ap[kf * 32];
        const bf16_t* wk = wp + (size_t)kf * 2048;
#pragma unroll
        for (int s = 0; s < 4; ++s) {
            bf16x8 w8 = *(const bf16x8*)&wk[s * 512];
            acc[s] = __builtin_amdgcn_mfma_f32_16x16x32_bf16(a8, w8, acc[s], 0, 0, 0);
        }
    }
#pragma unroll
    for (int s = 0; s < 4; ++s) *(f32x4*)&red[wg][mt][s][l * 4] = acc[s];
    __syncthreads();

    if (w < 4) {
        const int d = nb * 16 + (l & 15);
        const int rb = w * 16 + ((l >> 4) << 2);
        f32x4 v[4];
#pragma unroll
        for (int s = 0; s < 4; ++s)
            v[s] = *(const f32x4*)&red[0][w][s][l * 4] + *(const f32x4*)&red[1][w][s][l * 4];
#pragma unroll
        for (int j = 0; j < 4; ++j) {
            int row = rb + j;
            float gi = v[0][j] + bsum2[d];
            float gf = v[1][j] + bsum2[512 + d];
            float gg = v[2][j] + bsum2[1024 + d];
            float go = v[3][j] + bsum2[1536 + d];
            float cn = sigf(gf) * c2r[row * 512 + d] + sigf(gi) * tanhf(gg);
            c2w[row * 512 + d] = cn;
            h2w[row * 512 + d] = (bf16_t)(sigf(go) * tanhf(cn));
        }
    }
}

// ---------------------------------------------------------------------------
extern "C" void kernel_launch(void* const* d_in, const int* in_sizes, int n_in,
                              void* d_out, int out_size, void* d_ws, size_t ws_size,
                              hipStream_t stream)
{
    const float* features = (const float*)d_in[0];
    const int*   captions = (const int*)d_in[1];
    const float* emb   = (const float*)d_in[2];
    const float* W1    = (const float*)d_in[3];
    const float* b1    = (const float*)d_in[4];
    const float* W2    = (const float*)d_in[5];
    const float* b2    = (const float*)d_in[6];
    const float* V     = (const float*)d_in[7];
    const float* bV    = (const float*)d_in[8];
    const float* W_ih1 = (const float*)d_in[9];
    const float* W_hh1 = (const float*)d_in[10];
    const float* b_ih1 = (const float*)d_in[11];
    const float* b_hh1 = (const float*)d_in[12];
    const float* W_ih2 = (const float*)d_in[13];
    const float* W_hh2 = (const float*)d_in[14];
    const float* b_ih2 = (const float*)d_in[15];
    const float* b_hh2 = (const float*)d_in[16];
    const float* fc_W  = (const float*)d_in[17];
    const float* fc_b  = (const float*)d_in[18];
    float* out = (float*)d_out;

    char* ws = (char*)d_ws;
    size_t off = 0;
    auto alloc = [&](size_t nbytes) {
        char* pp = ws + off;
        off = (off + nbytes + 255) & ~(size_t)255;
        return pp;
    };
    bf16_t* featb  = (bf16_t*)alloc(3136L * 2048 * 2);
    bf16_t* fW1b   = (bf16_t*)alloc(3136L * 512 * 2);
    bf16_t* W1b    = (bf16_t*)alloc(512L * 2048 * 2);
    bf16_t* W2p    = (bf16_t*)alloc(512L * 512 * 2);
    bf16_t* Wihel  = (bf16_t*)alloc(2048L * 256 * 2);
    bf16_t* fp1    = (bf16_t*)alloc(2048L * 2560 * 2);
    bf16_t* fp2    = (bf16_t*)alloc(2048L * 1024 * 2);
    bf16_t* fcWb   = (bf16_t*)alloc((size_t)VPAD * 512 * 2);
    bf16_t* xgb    = (bf16_t*)alloc(1920L * 256 * 2);
    bf16_t* xembb  = (bf16_t*)alloc(1920L * 2048 * 2);
    float*  bsum1  = (float*)alloc(2048 * 4);
    float*  bsum2  = (float*)alloc(2048 * 4);
    bf16_t* ctxb   = (bf16_t*)alloc((size_t)B_ * ENC * 2);
    float*  hwb    = (float*)alloc((size_t)B_ * ATT * 4);
    float*  G1p    = (float*)alloc((size_t)KH1 * B_ * G4 * 4);
    bf16_t* h1s    = (bf16_t*)alloc((size_t)(T_ + 1) * SL * 2);
    bf16_t* h2s    = (bf16_t*)alloc((size_t)(T_ + 1) * SL * 2);
    float*  c1s    = (float*)alloc(2L * SL * 4);
    float*  c2s    = (float*)alloc(2L * SL * 4);

    prep_k<<<4096, 256, 0, stream>>>(
        b_ih1, b_hh1, bsum1, b_ih2, b_hh2, bsum2,
        W2, W2p, W1, W1b, W_ih1, Wihel, fp1,
        W_ih2, W_hh1, W_hh2, fp2, fc_W, fcWb,
        features, featb, captions, emb, xgb,
        h1s, h2s, c1s, c2s);

    mm_bf16<0><<<dim3(ATT / 64, (B_ * P_) / 64), 256, 0, stream>>>(
        featb, ENC, W1b, ENC, b1, nullptr, fW1b, ATT, ATT, ENC);
    mm_bf16<0><<<dim3(G4 / 64, (T_ * B_) / 64), 256, 0, stream>>>(
        xgb, EMBED, Wihel, EMBED, bsum1, nullptr, xembb, G4, G4, EMBED);

    // ---- recurrence: cooperative persistent kernel with guarded fallback ----
    int coopOK = 0;
    {
        int dev = 0;
        (void)hipGetDevice(&dev);
        int coopAttr = 0;
        (void)hipDeviceGetAttribute(&coopAttr, hipDeviceAttributeCooperativeLaunch, dev);
        int maxBlk = 0;
        (void)hipOccupancyMaxActiveBlocksPerMultiprocessor(
            &maxBlk, (const void*)persistent_k, 512, 0);
        if (coopAttr == 1 && maxBlk >= 1) {
            PP pp { featb, fW1b, W2p, fp1, fp2, xembb,
                    V, bV, b2, bsum2,
                    h1s, h2s, ctxb, hwb, c1s, c2s };
            void* args[] = { &pp };
            if (hipLaunchCooperativeKernel((const void*)persistent_k,
                                           dim3(256), dim3(512), args, 0, stream) == hipSuccess)
                coopOK = 1;
        }
    }
    if (!coopOK) {
        for (int t = 0; t < T_; ++t) {
            hw_k<<<32, 256, 0, stream>>>(h2s + (size_t)t * SL, W2p, b2, hwb);
            attn_k<<<B_, 256, 0, stream>>>(hwb, fW1b, V, bV, featb, ctxb);
            g1p_k<<<dim3(32, KH1), 256, 0, stream>>>(
                ctxb, h1s + (size_t)t * SL, fp1, G1p);
            pw1_k<<<128, 256, 0, stream>>>(
                G1p, xembb + (size_t)t * B_ * G4,
                c1s + (size_t)(t & 1) * SL, c1s + (size_t)((t + 1) & 1) * SL,
                h1s + (size_t)(t + 1) * SL);
            g2pw_k<<<32, 512, 0, stream>>>(
                h1s + (size_t)(t + 1) * SL, h2s + (size_t)t * SL, fp2, bsum2,
                c2s + (size_t)(t & 1) * SL, c2s + (size_t)((t + 1) & 1) * SL,
                h2s + (size_t)(t + 1) * SL);
        }
    }

    // out = h2(1..30) @ fc_W^T + fc_b  (f32 out, row remap t*64+b -> b*T+t)
    mm_bf16<2><<<dim3(VPAD / 64, (T_ * B_) / 64), 256, 0, stream>>>(
        h2s + SL, DEC, fcWb, DEC, fc_b, out, nullptr, VOCAB, VOCAB, DEC);
}